// Round 1
// baseline (753.244 us; speedup 1.0000x reference)
//
#include <hip/hip_runtime.h>

#define W 128
#define ROWS 32      // dst rows per block in fused_conv
#define BSHIFT 10    // 1024 dst ids per bucket
#define BSZ 1024

typedef short bf16x8 __attribute__((ext_vector_type(8)));
typedef float f32x4 __attribute__((ext_vector_type(4)));

__device__ __forceinline__ float lrelu(float x) { return x > 0.f ? x : 0.01f * x; }

// RTNE float -> bf16 (as ushort bit pattern)
__device__ __forceinline__ unsigned short f2bf(float f) {
    unsigned u = __float_as_uint(f);
    u += 0x7fffu + ((u >> 16) & 1u);
    return (unsigned short)(u >> 16);
}
__device__ __forceinline__ float bfu(unsigned short u) {
    return __uint_as_float(((unsigned)u) << 16);
}
__device__ __forceinline__ float4 bf4_to_f4(ushort4 u) {
    return make_float4(bfu(u.x), bfu(u.y), bfu(u.z), bfu(u.w));
}
__device__ __forceinline__ ushort4 f4_to_bf4(float4 f) {
    return make_ushort4(f2bf(f.x), f2bf(f.y), f2bf(f.z), f2bf(f.w));
}
// monotonic uint encoding of float (order-preserving): min(enc) == enc(min)
__device__ __forceinline__ unsigned enc_f(float f) {
    unsigned b = __float_as_uint(f);
    return (b & 0x80000000u) ? ~b : (b | 0x80000000u);
}
__device__ __forceinline__ float dec_f(unsigned e) {
    unsigned b = (e & 0x80000000u) ? (e ^ 0x80000000u) : ~e;
    return __uint_as_float(b);
}

// ---- initial embed: lrelu(in @ Wm + b) -> bf16 ----
template <int K>
__global__ void embed_kernel(const float* __restrict__ in, const float* __restrict__ Wm,
                             const float* __restrict__ bias, unsigned short* __restrict__ outb,
                             int n) {
    int t = blockIdx.x * 256 + threadIdx.x;
    int row = t >> 7, c = t & 127;
    if (row >= n) return;
    float s = bias[c];
#pragma unroll
    for (int k = 0; k < K; k++) s += in[row * K + k] * Wm[k * W + c];
    outb[(size_t)row * W + c] = f2bf(lrelu(s));
}

// ---- fused weight convert: 4x [256][128] fp32 -> [128][256] bf16 transposed ----
__global__ void wconv4_kernel(const float* __restrict__ W0, const float* __restrict__ W1,
                              const float* __restrict__ W2, const float* __restrict__ W3,
                              unsigned short* __restrict__ T0, unsigned short* __restrict__ T1,
                              unsigned short* __restrict__ T2, unsigned short* __restrict__ T3) {
    int which = blockIdx.x >> 7;
    const float* Wm = (which == 0) ? W0 : (which == 1) ? W1 : (which == 2) ? W2 : W3;
    unsigned short* Wt = (which == 0) ? T0 : (which == 1) ? T1 : (which == 2) ? T2 : T3;
    int i = (blockIdx.x & 127) * 256 + threadIdx.x;  // 32768 per matrix
    int k = i >> 7, n = i & 127;
    Wt[n * 256 + k] = f2bf(Wm[k * W + n]);
}

// ---- bucket-partitioned CSR build over concatenated dst domain ----
struct PairSrc {
    const int* d0; const int* s0; int n0;
    const int* d1; const int* s1; int n1;
    const int* d2; const int* s2; int n2;
    int NE, NF;
};

__device__ __forceinline__ void pair_at(const PairSrc& P, int g, int& dp, int& sp) {
    dp = -1; sp = 0;
    if (g < P.n0) { dp = P.d0[g]; sp = P.s0[g]; }
    else if (g < P.n0 + P.n1) { int j = g - P.n0; dp = P.NE + P.d1[j]; sp = P.s1[j]; }
    else if (g < P.n0 + P.n1 + P.n2) { int j = g - P.n0 - P.n1; dp = P.NE + P.NF + P.d2[j]; sp = P.s2[j]; }
}

#define CHUNK 4096

__global__ __launch_bounds__(256) void part_hist(PairSrc P, int* __restrict__ gcnt) {
    __shared__ int hist[512];
    int t = threadIdx.x;
    for (int j = t; j < 512; j += 256) hist[j] = 0;
    __syncthreads();
    int g0 = blockIdx.x * CHUNK;
#pragma unroll
    for (int k = 0; k < 16; k++) {
        int dp, sp;
        pair_at(P, g0 + k * 256 + t, dp, sp);
        if (dp >= 0) atomicAdd(&hist[dp >> BSHIFT], 1);
    }
    __syncthreads();
    for (int j = t; j < 512; j += 256)
        if (hist[j]) atomicAdd(&gcnt[j], hist[j]);
}

__global__ void bucket_scan(const int* __restrict__ gcnt, int* __restrict__ goff,
                            int* __restrict__ gcur, int NB, int NP) {
    __shared__ int s[512];
    int t = threadIdx.x;
    int v = (t < NB) ? gcnt[t] : 0;
    s[t] = v;
    __syncthreads();
    for (int off = 1; off < 512; off <<= 1) {
        int add = (t >= off) ? s[t - off] : 0;
        __syncthreads();
        s[t] += add;
        __syncthreads();
    }
    if (t < NB) {
        int excl = s[t] - v;
        goff[t] = excl;
        gcur[t] = excl;
    }
    if (t == 0) goff[NB] = NP;
}

__global__ __launch_bounds__(256) void part_scatter(PairSrc P, int* __restrict__ gcur,
                                                    int2* __restrict__ pairs) {
    __shared__ int hist[512];
    __shared__ int base[512];
    int t = threadIdx.x;
    for (int j = t; j < 512; j += 256) hist[j] = 0;
    __syncthreads();
    int g0 = blockIdx.x * CHUNK;
    int dv[16], sv[16], rk[16];
#pragma unroll
    for (int k = 0; k < 16; k++) {
        pair_at(P, g0 + k * 256 + t, dv[k], sv[k]);
        rk[k] = (dv[k] >= 0) ? atomicAdd(&hist[dv[k] >> BSHIFT], 1) : 0;
    }
    __syncthreads();
    for (int j = t; j < 512; j += 256)
        base[j] = hist[j] ? atomicAdd(&gcur[j], hist[j]) : 0;
    __syncthreads();
#pragma unroll
    for (int k = 0; k < 16; k++) {
        if (dv[k] >= 0) pairs[base[dv[k] >> BSHIFT] + rk[k]] = make_int2(dv[k], sv[k]);
    }
}

// one block per bucket: LDS counting sort -> rowptr + cs (int2: x=src, y=dst)
__global__ __launch_bounds__(256) void bucket_sort(const int2* __restrict__ pairs,
                                                   const int* __restrict__ goff, int D, int NP,
                                                   int* __restrict__ rowptr,
                                                   int2* __restrict__ cs) {
    __shared__ int hist[BSZ];
    __shared__ int base[BSZ];
    __shared__ int tsum[256];
    int b = blockIdx.x, t = threadIdx.x;
    int d0 = b << BSHIFT;
    int roff = goff[b], rend = goff[b + 1], cnt = rend - roff;
    for (int j = t; j < BSZ; j += 256) hist[j] = 0;
    __syncthreads();
    for (int i = t; i < cnt; i += 256) {
        int2 pr = pairs[roff + i];
        atomicAdd(&hist[pr.x - d0], 1);
    }
    __syncthreads();
    int loc[4], s0 = 0;
#pragma unroll
    for (int k = 0; k < 4; k++) {
        loc[k] = s0;
        s0 += hist[t * 4 + k];
    }
    tsum[t] = s0;
    __syncthreads();
    for (int off = 1; off < 256; off <<= 1) {
        int add = (t >= off) ? tsum[t - off] : 0;
        __syncthreads();
        tsum[t] += add;
        __syncthreads();
    }
    int ebase = tsum[t] - s0;
#pragma unroll
    for (int k = 0; k < 4; k++) base[t * 4 + k] = ebase + loc[k];
    __syncthreads();
    for (int j = t; j < BSZ; j += 256) {
        int d = d0 + j;
        if (d < D) rowptr[d] = roff + base[j];
    }
    if (b == 0 && t == 0) rowptr[D] = NP;
    for (int j = t; j < BSZ; j += 256) hist[j] = base[j];
    __syncthreads();
    for (int i = t; i < cnt; i += 256) {
        int2 pr = pairs[roff + i];
        int pos = roff + atomicAdd(&hist[pr.x - d0], 1);
        cs[pos] = make_int2(pr.y, pr.x);
    }
}

// =====================================================================
// fused conv, edge-parallel gather:
//   phase A: init LDS mins (enc-fp32) ; load own xd rows + degrees
//   phase B: pipelined 4-deep pair stream -> bank-conflict-free LDS atomicMin
//            min layout: channel (4*li+k) of row d lives at smem[d*SMW + 32*k + li]
//            (stride-32 interleave: each ds_atomic_min hits all 32 banks)
//   phase C: mins -> mx ; rewrite LDS as bf16 h tile (union, same 16.9KB)
//   phase D: MFMA MLP + residual epilogue
// =====================================================================
#define SMW 132  // dwords per LDS row (128 + 4 pad); 132*4B == 264 shorts

template <bool OUT_F32>
__global__ __launch_bounds__(256) void fused_conv_ep(
    const unsigned short* __restrict__ xsb, const unsigned short* __restrict__ xdb,
    unsigned short* __restrict__ out_b, float* __restrict__ out_f,
    const int* __restrict__ rowptr, const int2* __restrict__ cs,
    int off_conv, const unsigned short* __restrict__ Wt, const float* __restrict__ bias,
    int n_dst) {
    __shared__ unsigned smem[ROWS * SMW];  // union: enc-fp32 mins, then bf16 h
    int t = threadIdx.x;
    int wave = t >> 6, lane = t & 63;
    int li = lane & 31, halfIdx = t >> 5;  // 0..7
    int r0 = blockIdx.x * ROWS;

    for (int j = t; j < ROWS * SMW; j += 256) smem[j] = 0xFFFFFFFFu;

    int rbase = halfIdx * 4;
    ushort4 xdu[4];
    int degv[4];
#pragma unroll
    for (int rr = 0; rr < 4; rr++) {
        int d = r0 + rbase + rr;
        xdu[rr] = make_ushort4(0, 0, 0, 0);
        degv[rr] = 0;
        if (d < n_dst) {
            xdu[rr] = ((const ushort4*)xdb)[(size_t)d * 32 + li];
            degv[rr] = rowptr[d + 1] - rowptr[d];
        }
    }
    __syncthreads();

    // --- phase B: edge-parallel gather-min, software-pipelined (idx prefetch
    //     issued between xs loads and atomics so it flies across iterations)
    int rEnd = (r0 + ROWS < n_dst) ? r0 + ROWS : n_dst;
    int prBeg = rowptr[r0], prEnd = rowptr[rEnd];
    const ushort4* xs4 = (const ushort4*)xsb;
    int dbase = off_conv + r0;

    int p = prBeg + halfIdx;
    int cnt_h = prEnd - p;
    cnt_h = cnt_h > 0 ? ((cnt_h + 7) >> 3) : 0;  // pairs in this stream
    int ng = cnt_h >> 2;                          // full groups of 4
    int pe1 = prEnd - 1;
    int2 i0, i1, i2, i3;
    if (ng > 0) {
        i0 = cs[p];      i1 = cs[p + 8];
        i2 = cs[p + 16]; i3 = cs[p + 24];
    }
    for (int g = 0; g < ng; g++) {
        float4 f0 = bf4_to_f4(xs4[(size_t)i0.x * 32 + li]);
        float4 f1 = bf4_to_f4(xs4[(size_t)i1.x * 32 + li]);
        float4 f2 = bf4_to_f4(xs4[(size_t)i2.x * 32 + li]);
        float4 f3 = bf4_to_f4(xs4[(size_t)i3.x * 32 + li]);
        int pn = p + 32;
        int q0 = pn      < pe1 ? pn      : pe1;   // clamped prefetch (garbage
        int q1 = pn + 8  < pe1 ? pn + 8  : pe1;   // beyond last group is unused)
        int q2 = pn + 16 < pe1 ? pn + 16 : pe1;
        int q3 = pn + 24 < pe1 ? pn + 24 : pe1;
        int2 j0 = cs[q0], j1 = cs[q1], j2 = cs[q2], j3 = cs[q3];
        unsigned* m0 = &smem[(i0.y - dbase) * SMW + li];
        unsigned* m1 = &smem[(i1.y - dbase) * SMW + li];
        unsigned* m2 = &smem[(i2.y - dbase) * SMW + li];
        unsigned* m3 = &smem[(i3.y - dbase) * SMW + li];
        atomicMin(&m0[0], enc_f(f0.x)); atomicMin(&m0[32], enc_f(f0.y));
        atomicMin(&m0[64], enc_f(f0.z)); atomicMin(&m0[96], enc_f(f0.w));
        atomicMin(&m1[0], enc_f(f1.x)); atomicMin(&m1[32], enc_f(f1.y));
        atomicMin(&m1[64], enc_f(f1.z)); atomicMin(&m1[96], enc_f(f1.w));
        atomicMin(&m2[0], enc_f(f2.x)); atomicMin(&m2[32], enc_f(f2.y));
        atomicMin(&m2[64], enc_f(f2.z)); atomicMin(&m2[96], enc_f(f2.w));
        atomicMin(&m3[0], enc_f(f3.x)); atomicMin(&m3[32], enc_f(f3.y));
        atomicMin(&m3[64], enc_f(f3.z)); atomicMin(&m3[96], enc_f(f3.w));
        p = pn;
        i0 = j0; i1 = j1; i2 = j2; i3 = j3;
    }
    int rem = cnt_h & 3;
    for (int k = 0; k < rem; k++) {
        int pp = p + k * 8;
        int2 pr = cs[pp];
        float4 f = bf4_to_f4(xs4[(size_t)pr.x * 32 + li]);
        unsigned* m = &smem[(pr.y - dbase) * SMW + li];
        atomicMin(&m[0], enc_f(f.x)); atomicMin(&m[32], enc_f(f.y));
        atomicMin(&m[64], enc_f(f.z)); atomicMin(&m[96], enc_f(f.w));
    }
    __syncthreads();

    // --- phase C: mins -> mx, then rewrite smem as h
    float4 mxv[4];
#pragma unroll
    for (int rr = 0; rr < 4; rr++) {
        int r = rbase + rr;
        const unsigned* mrow = &smem[r * SMW + li];
        unsigned mu0 = mrow[0], mu1 = mrow[32], mu2 = mrow[64], mu3 = mrow[96];
        float4 xdv = bf4_to_f4(xdu[rr]);
        mxv[rr].x = degv[rr] ? (xdv.x - dec_f(mu0)) : 0.f;
        mxv[rr].y = degv[rr] ? (xdv.y - dec_f(mu1)) : 0.f;
        mxv[rr].z = degv[rr] ? (xdv.z - dec_f(mu2)) : 0.f;
        mxv[rr].w = degv[rr] ? (xdv.w - dec_f(mu3)) : 0.f;
    }
    __syncthreads();
    unsigned short* h = (unsigned short*)smem;  // stride 264 shorts per row
#pragma unroll
    for (int rr = 0; rr < 4; rr++) {
        int r = rbase + rr;
        *(ushort4*)&h[r * 264 + 4 * li] = xdu[rr];
        *(ushort4*)&h[r * 264 + 128 + 4 * li] = f4_to_bf4(mxv[rr]);
    }
    __syncthreads();

    // --- phase D: MFMA
    int rt = wave >> 1;
    int ctbase = (wave & 1) * 4;
    int m = lane & 15, q = lane >> 4;
    f32x4 acc[4];
#pragma unroll
    for (int ct = 0; ct < 4; ct++) acc[ct] = (f32x4){0.f, 0.f, 0.f, 0.f};
    for (int k0 = 0; k0 < 256; k0 += 32) {
        bf16x8 a = *(const bf16x8*)&h[(rt * 16 + m) * 264 + k0 + q * 8];
#pragma unroll
        for (int ct = 0; ct < 4; ct++) {
            int n = (ctbase + ct) * 16 + m;
            bf16x8 b = *(const bf16x8*)&Wt[n * 256 + k0 + q * 8];
            acc[ct] = __builtin_amdgcn_mfma_f32_16x16x32_bf16(a, b, acc[ct], 0, 0, 0);
        }
    }
#pragma unroll
    for (int ct = 0; ct < 4; ct++) {
        int col = (ctbase + ct) * 16 + m;
        float bc = bias[col];
#pragma unroll
        for (int reg = 0; reg < 4; reg++) {
            int r_l = rt * 16 + q * 4 + reg;
            int row = r0 + r_l;
            if (row < n_dst) {
                float xold = bfu(h[r_l * 264 + col]);
                float val = xold + lrelu(acc[ct][reg] + bc);
                if (OUT_F32) out_f[(size_t)row * W + col] = val;
                else out_b[(size_t)row * W + col] = f2bf(val);
            }
        }
    }
}

// ---- v2e variant: src row = on-the-fly vertex embed (12 B loads) ----
// same pipelined 4-deep gather as the generic conv (was 1-deep: the latency
// chain cs -> verts -> atomics was fully exposed, 8 serial iterations/stream)
__global__ __launch_bounds__(256) void fused_conv_v2e_ep(
    const float* __restrict__ verts, const float* __restrict__ Wv, const float* __restrict__ bv,
    unsigned short* __restrict__ x_eb, const int* __restrict__ rowptr,
    const int2* __restrict__ cs,
    const unsigned short* __restrict__ Wt, const float* __restrict__ bias, int n_dst) {
    __shared__ unsigned smem[ROWS * SMW];
    int t = threadIdx.x;
    int wave = t >> 6, lane = t & 63;
    int li = lane & 31, halfIdx = t >> 5;
    int r0 = blockIdx.x * ROWS;

    for (int j = t; j < ROWS * SMW; j += 256) smem[j] = 0xFFFFFFFFu;

    float4 wv0 = *(const float4*)&Wv[0 * W + 4 * li];
    float4 wv1 = *(const float4*)&Wv[1 * W + 4 * li];
    float4 wv2 = *(const float4*)&Wv[2 * W + 4 * li];
    float4 bvv = *(const float4*)&bv[4 * li];

    int rbase = halfIdx * 4;
    ushort4 xdu[4];
    int degv[4];
#pragma unroll
    for (int rr = 0; rr < 4; rr++) {
        int d = r0 + rbase + rr;
        xdu[rr] = make_ushort4(0, 0, 0, 0);
        degv[rr] = 0;
        if (d < n_dst) {
            xdu[rr] = ((const ushort4*)x_eb)[(size_t)d * 32 + li];
            degv[rr] = rowptr[d + 1] - rowptr[d];
        }
    }
    __syncthreads();

    int rEnd = (r0 + ROWS < n_dst) ? r0 + ROWS : n_dst;
    int prBeg = rowptr[r0], prEnd = rowptr[rEnd];
    int dbase = r0;  // conv1 offset is 0

    int p = prBeg + halfIdx;
    int cnt_h = prEnd - p;
    cnt_h = cnt_h > 0 ? ((cnt_h + 7) >> 3) : 0;
    int ng = cnt_h >> 2;
    int pe1 = prEnd - 1;
    int2 i0, i1, i2, i3;
    if (ng > 0) {
        i0 = cs[p];      i1 = cs[p + 8];
        i2 = cs[p + 16]; i3 = cs[p + 24];
    }
    for (int g = 0; g < ng; g++) {
        float a00 = verts[3 * i0.x], a01 = verts[3 * i0.x + 1], a02 = verts[3 * i0.x + 2];
        float a10 = verts[3 * i1.x], a11 = verts[3 * i1.x + 1], a12 = verts[3 * i1.x + 2];
        float a20 = verts[3 * i2.x], a21 = verts[3 * i2.x + 1], a22 = verts[3 * i2.x + 2];
        float a30 = verts[3 * i3.x], a31 = verts[3 * i3.x + 1], a32 = verts[3 * i3.x + 2];
        int pn = p + 32;
        int q0 = pn      < pe1 ? pn      : pe1;
        int q1 = pn + 8  < pe1 ? pn + 8  : pe1;
        int q2 = pn + 16 < pe1 ? pn + 16 : pe1;
        int q3 = pn + 24 < pe1 ? pn + 24 : pe1;
        int2 j0 = cs[q0], j1 = cs[q1], j2 = cs[q2], j3 = cs[q3];
        unsigned* m0 = &smem[(i0.y - dbase) * SMW + li];
        unsigned* m1 = &smem[(i1.y - dbase) * SMW + li];
        unsigned* m2 = &smem[(i2.y - dbase) * SMW + li];
        unsigned* m3 = &smem[(i3.y - dbase) * SMW + li];
        float4 e;
        e.x = lrelu(bvv.x + a00 * wv0.x + a01 * wv1.x + a02 * wv2.x);
        e.y = lrelu(bvv.y + a00 * wv0.y + a01 * wv1.y + a02 * wv2.y);
        e.z = lrelu(bvv.z + a00 * wv0.z + a01 * wv1.z + a02 * wv2.z);
        e.w = lrelu(bvv.w + a00 * wv0.w + a01 * wv1.w + a02 * wv2.w);
        atomicMin(&m0[0], enc_f(e.x)); atomicMin(&m0[32], enc_f(e.y));
        atomicMin(&m0[64], enc_f(e.z)); atomicMin(&m0[96], enc_f(e.w));
        e.x = lrelu(bvv.x + a10 * wv0.x + a11 * wv1.x + a12 * wv2.x);
        e.y = lrelu(bvv.y + a10 * wv0.y + a11 * wv1.y + a12 * wv2.y);
        e.z = lrelu(bvv.z + a10 * wv0.z + a11 * wv1.z + a12 * wv2.z);
        e.w = lrelu(bvv.w + a10 * wv0.w + a11 * wv1.w + a12 * wv2.w);
        atomicMin(&m1[0], enc_f(e.x)); atomicMin(&m1[32], enc_f(e.y));
        atomicMin(&m1[64], enc_f(e.z)); atomicMin(&m1[96], enc_f(e.w));
        e.x = lrelu(bvv.x + a20 * wv0.x + a21 * wv1.x + a22 * wv2.x);
        e.y = lrelu(bvv.y + a20 * wv0.y + a21 * wv1.y + a22 * wv2.y);
        e.z = lrelu(bvv.z + a20 * wv0.z + a21 * wv1.z + a22 * wv2.z);
        e.w = lrelu(bvv.w + a20 * wv0.w + a21 * wv1.w + a22 * wv2.w);
        atomicMin(&m2[0], enc_f(e.x)); atomicMin(&m2[32], enc_f(e.y));
        atomicMin(&m2[64], enc_f(e.z)); atomicMin(&m2[96], enc_f(e.w));
        e.x = lrelu(bvv.x + a30 * wv0.x + a31 * wv1.x + a32 * wv2.x);
        e.y = lrelu(bvv.y + a30 * wv0.y + a31 * wv1.y + a32 * wv2.y);
        e.z = lrelu(bvv.z + a30 * wv0.z + a31 * wv1.z + a32 * wv2.z);
        e.w = lrelu(bvv.w + a30 * wv0.w + a31 * wv1.w + a32 * wv2.w);
        atomicMin(&m3[0], enc_f(e.x)); atomicMin(&m3[32], enc_f(e.y));
        atomicMin(&m3[64], enc_f(e.z)); atomicMin(&m3[96], enc_f(e.w));
        p = pn;
        i0 = j0; i1 = j1; i2 = j2; i3 = j3;
    }
    int rem = cnt_h & 3;
    for (int k = 0; k < rem; k++) {
        int pp = p + k * 8;
        int2 pr = cs[pp];
        float a0 = verts[3 * pr.x], a1 = verts[3 * pr.x + 1], a2 = verts[3 * pr.x + 2];
        float4 e;
        e.x = lrelu(bvv.x + a0 * wv0.x + a1 * wv1.x + a2 * wv2.x);
        e.y = lrelu(bvv.y + a0 * wv0.y + a1 * wv1.y + a2 * wv2.y);
        e.z = lrelu(bvv.z + a0 * wv0.z + a1 * wv1.z + a2 * wv2.z);
        e.w = lrelu(bvv.w + a0 * wv0.w + a1 * wv1.w + a2 * wv2.w);
        unsigned* m = &smem[(pr.y - dbase) * SMW + li];
        atomicMin(&m[0], enc_f(e.x)); atomicMin(&m[32], enc_f(e.y));
        atomicMin(&m[64], enc_f(e.z)); atomicMin(&m[96], enc_f(e.w));
    }
    __syncthreads();

    float4 mxv[4];
#pragma unroll
    for (int rr = 0; rr < 4; rr++) {
        int r = rbase + rr;
        const unsigned* mrow = &smem[r * SMW + li];
        unsigned mu0 = mrow[0], mu1 = mrow[32], mu2 = mrow[64], mu3 = mrow[96];
        float4 xdv = bf4_to_f4(xdu[rr]);
        mxv[rr].x = degv[rr] ? (xdv.x - dec_f(mu0)) : 0.f;
        mxv[rr].y = degv[rr] ? (xdv.y - dec_f(mu1)) : 0.f;
        mxv[rr].z = degv[rr] ? (xdv.z - dec_f(mu2)) : 0.f;
        mxv[rr].w = degv[rr] ? (xdv.w - dec_f(mu3)) : 0.f;
    }
    __syncthreads();
    unsigned short* h = (unsigned short*)smem;
#pragma unroll
    for (int rr = 0; rr < 4; rr++) {
        int r = rbase + rr;
        *(ushort4*)&h[r * 264 + 4 * li] = xdu[rr];
        *(ushort4*)&h[r * 264 + 128 + 4 * li] = f4_to_bf4(mxv[rr]);
    }
    __syncthreads();

    int rt = wave >> 1;
    int ctbase = (wave & 1) * 4;
    int m = lane & 15, q = lane >> 4;
    f32x4 acc[4];
#pragma unroll
    for (int ct = 0; ct < 4; ct++) acc[ct] = (f32x4){0.f, 0.f, 0.f, 0.f};
    for (int k0 = 0; k0 < 256; k0 += 32) {
        bf16x8 a = *(const bf16x8*)&h[(rt * 16 + m) * 264 + k0 + q * 8];
#pragma unroll
        for (int ct = 0; ct < 4; ct++) {
            int n = (ctbase + ct) * 16 + m;
            bf16x8 b = *(const bf16x8*)&Wt[n * 256 + k0 + q * 8];
            acc[ct] = __builtin_amdgcn_mfma_f32_16x16x32_bf16(a, b, acc[ct], 0, 0, 0);
        }
    }
#pragma unroll
    for (int ct = 0; ct < 4; ct++) {
        int col = (ctbase + ct) * 16 + m;
        float bc = bias[col];
#pragma unroll
        for (int reg = 0; reg < 4; reg++) {
            int r_l = rt * 16 + q * 4 + reg;
            int row = r0 + r_l;
            if (row < n_dst) {
                float xold = bfu(h[r_l * 264 + col]);
                x_eb[(size_t)row * W + col] = f2bf(xold + lrelu(acc[ct][reg] + bc));
            }
        }
    }
}

static inline char* alignp(char* p, size_t a) {
    return (char*)(((uintptr_t)p + a - 1) & ~(uintptr_t)(a - 1));
}

extern "C" void kernel_launch(void* const* d_in, const int* in_sizes, int n_in,
                              void* d_out, int out_size, void* d_ws, size_t ws_size,
                              hipStream_t stream) {
    const float* vertices = (const float*)d_in[0];
    const float* edges    = (const float*)d_in[1];
    const float* faces    = (const float*)d_in[2];
    const int* etv_v   = (const int*)d_in[3];
    const int* etv_e   = (const int*)d_in[4];
    const int* fte_e   = (const int*)d_in[5];
    const int* fte_f   = (const int*)d_in[6];
    const int* ftf_src = (const int*)d_in[7];
    const int* ftf_dst = (const int*)d_in[8];
    const float* Wv   = (const float*)d_in[9];
    const float* bv   = (const float*)d_in[10];
    const float* We   = (const float*)d_in[11];
    const float* be   = (const float*)d_in[12];
    const float* Wf   = (const float*)d_in[13];
    const float* bf_  = (const float*)d_in[14];
    const float* Wv2e = (const float*)d_in[15];
    const float* bv2e = (const float*)d_in[16];
    const float* We2f = (const float*)d_in[17];
    const float* be2f = (const float*)d_in[18];
    const float* Wm0  = (const float*)d_in[19];
    const float* bm0  = (const float*)d_in[20];
    const float* Wm1  = (const float*)d_in[21];
    const float* bm1  = (const float*)d_in[22];

    const int NV = in_sizes[0] / 3;
    const int NE = in_sizes[1] / 12;
    const int NF = in_sizes[2] / 14;
    const int N_EV = in_sizes[3];
    const int N_FE = in_sizes[5];
    const int N_FF = in_sizes[7];
    (void)NV; (void)n_in; (void)out_size; (void)ws_size;

    const int D = NE + NF + NF;
    const int NP = N_EV + N_FE + N_FF;
    const int NB = (D + BSZ - 1) >> BSHIFT;

    // ---- ws layout ----
    char* p = (char*)d_ws;
    unsigned short* x_eb = (unsigned short*)p;  p += (size_t)NE * W * sizeof(unsigned short);
    unsigned short* f0b  = (unsigned short*)p;  p += (size_t)NF * W * sizeof(unsigned short);
    unsigned short* f1b  = (unsigned short*)p;  p += (size_t)NF * W * sizeof(unsigned short);
    p = alignp(p, 16);
    int2* pairs = (int2*)p;                     p += (size_t)NP * sizeof(int2);
    int2* cs    = (int2*)p;                     p += (size_t)NP * sizeof(int2);
    int* rowptr = (int*)p;                      p += (size_t)(D + 1) * sizeof(int);
    int* gcnt   = (int*)p;                      p += 512 * sizeof(int);
    int* goff   = (int*)p;                      p += 513 * sizeof(int);
    int* gcur   = (int*)p;                      p += 512 * sizeof(int);
    p = alignp(p, 16);
    unsigned short* Wt0 = (unsigned short*)p;   p += (size_t)32768 * sizeof(unsigned short);
    unsigned short* Wt1 = (unsigned short*)p;   p += (size_t)32768 * sizeof(unsigned short);
    unsigned short* Wt2 = (unsigned short*)p;   p += (size_t)32768 * sizeof(unsigned short);
    unsigned short* Wt3 = (unsigned short*)p;   p += (size_t)32768 * sizeof(unsigned short);

    float* out_f = (float*)d_out;
    const int TB = 256;

    // ---- embeds (bf16); x_v folded into conv1 ----
    embed_kernel<12><<<((size_t)NE * W + TB - 1) / TB, TB, 0, stream>>>(edges, We, be, x_eb, NE);
    embed_kernel<14><<<((size_t)NF * W + TB - 1) / TB, TB, 0, stream>>>(faces, Wf, bf_, f0b, NF);
    wconv4_kernel<<<512, TB, 0, stream>>>(Wv2e, We2f, Wm0, Wm1, Wt0, Wt1, Wt2, Wt3);

    // ---- bucket-partitioned CSR build ----
    PairSrc P = {etv_e, etv_v, N_EV, fte_f, fte_e, N_FE, ftf_dst, ftf_src, N_FF, NE, NF};
    (void)hipMemsetAsync(gcnt, 0, 512 * sizeof(int), stream);
    int ablocks = (NP + CHUNK - 1) / CHUNK;
    part_hist<<<ablocks, TB, 0, stream>>>(P, gcnt);
    bucket_scan<<<1, 512, 0, stream>>>(gcnt, goff, gcur, NB, NP);
    part_scatter<<<ablocks, TB, 0, stream>>>(P, gcur, pairs);
    bucket_sort<<<NB, TB, 0, stream>>>(pairs, goff, D, NP, rowptr, cs);

    // ---- fused convs (edge-parallel gather, pipelined) ----
    fused_conv_v2e_ep<<<(NE + ROWS - 1) / ROWS, TB, 0, stream>>>(vertices, Wv, bv, x_eb, rowptr,
                                                                 cs, Wt0, bv2e, NE);
    fused_conv_ep<false><<<(NF + ROWS - 1) / ROWS, TB, 0, stream>>>(
        x_eb, f0b, f0b, nullptr, rowptr + NE, cs, NE, Wt1, be2f, NF);
    fused_conv_ep<false><<<(NF + ROWS - 1) / ROWS, TB, 0, stream>>>(
        f0b, f0b, f1b, nullptr, rowptr + NE + NF, cs, NE + NF, Wt2, bm0, NF);
    fused_conv_ep<true><<<(NF + ROWS - 1) / ROWS, TB, 0, stream>>>(
        f1b, f1b, nullptr, out_f, rowptr + NE + NF, cs, NE + NF, Wt3, bm1, NF);
}

// Round 2
// 748.240 us; speedup vs baseline: 1.0067x; 1.0067x over previous
//
#include <hip/hip_runtime.h>

#define W 128
#define ROWS 32      // dst rows per block in fused_conv
#define BSHIFT 10    // 1024 dst ids per bucket
#define BSZ 1024

typedef short bf16x8 __attribute__((ext_vector_type(8)));
typedef float f32x4 __attribute__((ext_vector_type(4)));

__device__ __forceinline__ float lrelu(float x) { return x > 0.f ? x : 0.01f * x; }

// RTNE float -> bf16 (as ushort bit pattern)
__device__ __forceinline__ unsigned short f2bf(float f) {
    unsigned u = __float_as_uint(f);
    u += 0x7fffu + ((u >> 16) & 1u);
    return (unsigned short)(u >> 16);
}
__device__ __forceinline__ float bfu(unsigned short u) {
    return __uint_as_float(((unsigned)u) << 16);
}
__device__ __forceinline__ float4 bf4_to_f4(ushort4 u) {
    return make_float4(bfu(u.x), bfu(u.y), bfu(u.z), bfu(u.w));
}
__device__ __forceinline__ ushort4 f4_to_bf4(float4 f) {
    return make_ushort4(f2bf(f.x), f2bf(f.y), f2bf(f.z), f2bf(f.w));
}
__device__ __forceinline__ float4 fmin4(float4 a, float4 b) {
    return make_float4(fminf(a.x, b.x), fminf(a.y, b.y), fminf(a.z, b.z), fminf(a.w, b.w));
}

// ---- initial embed: lrelu(in @ Wm + b) -> bf16 ----
template <int K>
__global__ void embed_kernel(const float* __restrict__ in, const float* __restrict__ Wm,
                             const float* __restrict__ bias, unsigned short* __restrict__ outb,
                             int n) {
    int t = blockIdx.x * 256 + threadIdx.x;
    int row = t >> 7, c = t & 127;
    if (row >= n) return;
    float s = bias[c];
#pragma unroll
    for (int k = 0; k < K; k++) s += in[row * K + k] * Wm[k * W + c];
    outb[(size_t)row * W + c] = f2bf(lrelu(s));
}

// ---- fused weight convert: 4x [256][128] fp32 -> [128][256] bf16 transposed ----
__global__ void wconv4_kernel(const float* __restrict__ W0, const float* __restrict__ W1,
                              const float* __restrict__ W2, const float* __restrict__ W3,
                              unsigned short* __restrict__ T0, unsigned short* __restrict__ T1,
                              unsigned short* __restrict__ T2, unsigned short* __restrict__ T3) {
    int which = blockIdx.x >> 7;
    const float* Wm = (which == 0) ? W0 : (which == 1) ? W1 : (which == 2) ? W2 : W3;
    unsigned short* Wt = (which == 0) ? T0 : (which == 1) ? T1 : (which == 2) ? T2 : T3;
    int i = (blockIdx.x & 127) * 256 + threadIdx.x;  // 32768 per matrix
    int k = i >> 7, n = i & 127;
    Wt[n * 256 + k] = f2bf(Wm[k * W + n]);
}

// ---- bucket-partitioned CSR build over concatenated dst domain ----
struct PairSrc {
    const int* d0; const int* s0; int n0;
    const int* d1; const int* s1; int n1;
    const int* d2; const int* s2; int n2;
    int NE, NF;
};

__device__ __forceinline__ void pair_at(const PairSrc& P, int g, int& dp, int& sp) {
    dp = -1; sp = 0;
    if (g < P.n0) { dp = P.d0[g]; sp = P.s0[g]; }
    else if (g < P.n0 + P.n1) { int j = g - P.n0; dp = P.NE + P.d1[j]; sp = P.s1[j]; }
    else if (g < P.n0 + P.n1 + P.n2) { int j = g - P.n0 - P.n1; dp = P.NE + P.NF + P.d2[j]; sp = P.s2[j]; }
}

#define CHUNK 4096

__global__ __launch_bounds__(256) void part_hist(PairSrc P, int* __restrict__ gcnt) {
    __shared__ int hist[512];
    int t = threadIdx.x;
    for (int j = t; j < 512; j += 256) hist[j] = 0;
    __syncthreads();
    int g0 = blockIdx.x * CHUNK;
#pragma unroll
    for (int k = 0; k < 16; k++) {
        int dp, sp;
        pair_at(P, g0 + k * 256 + t, dp, sp);
        if (dp >= 0) atomicAdd(&hist[dp >> BSHIFT], 1);
    }
    __syncthreads();
    for (int j = t; j < 512; j += 256)
        if (hist[j]) atomicAdd(&gcnt[j], hist[j]);
}

__global__ void bucket_scan(const int* __restrict__ gcnt, int* __restrict__ goff,
                            int* __restrict__ gcur, int NB, int NP) {
    __shared__ int s[512];
    int t = threadIdx.x;
    int v = (t < NB) ? gcnt[t] : 0;
    s[t] = v;
    __syncthreads();
    for (int off = 1; off < 512; off <<= 1) {
        int add = (t >= off) ? s[t - off] : 0;
        __syncthreads();
        s[t] += add;
        __syncthreads();
    }
    if (t < NB) {
        int excl = s[t] - v;
        goff[t] = excl;
        gcur[t] = excl;
    }
    if (t == 0) goff[NB] = NP;
}

__global__ __launch_bounds__(256) void part_scatter(PairSrc P, int* __restrict__ gcur,
                                                    int2* __restrict__ pairs) {
    __shared__ int hist[512];
    __shared__ int base[512];
    int t = threadIdx.x;
    for (int j = t; j < 512; j += 256) hist[j] = 0;
    __syncthreads();
    int g0 = blockIdx.x * CHUNK;
    int dv[16], sv[16], rk[16];
#pragma unroll
    for (int k = 0; k < 16; k++) {
        pair_at(P, g0 + k * 256 + t, dv[k], sv[k]);
        rk[k] = (dv[k] >= 0) ? atomicAdd(&hist[dv[k] >> BSHIFT], 1) : 0;
    }
    __syncthreads();
    for (int j = t; j < 512; j += 256)
        base[j] = hist[j] ? atomicAdd(&gcur[j], hist[j]) : 0;
    __syncthreads();
#pragma unroll
    for (int k = 0; k < 16; k++) {
        if (dv[k] >= 0) pairs[base[dv[k] >> BSHIFT] + rk[k]] = make_int2(dv[k], sv[k]);
    }
}

// one block per bucket: LDS counting sort -> rowptr + ci (src only; dst is
// implicit from rowptr segmentation in the row-parallel conv)
__global__ __launch_bounds__(256) void bucket_sort(const int2* __restrict__ pairs,
                                                   const int* __restrict__ goff, int D, int NP,
                                                   int* __restrict__ rowptr,
                                                   int* __restrict__ ci) {
    __shared__ int hist[BSZ];
    __shared__ int base[BSZ];
    __shared__ int tsum[256];
    int b = blockIdx.x, t = threadIdx.x;
    int d0 = b << BSHIFT;
    int roff = goff[b], rend = goff[b + 1], cnt = rend - roff;
    for (int j = t; j < BSZ; j += 256) hist[j] = 0;
    __syncthreads();
    for (int i = t; i < cnt; i += 256) {
        int2 pr = pairs[roff + i];
        atomicAdd(&hist[pr.x - d0], 1);
    }
    __syncthreads();
    int loc[4], s0 = 0;
#pragma unroll
    for (int k = 0; k < 4; k++) {
        loc[k] = s0;
        s0 += hist[t * 4 + k];
    }
    tsum[t] = s0;
    __syncthreads();
    for (int off = 1; off < 256; off <<= 1) {
        int add = (t >= off) ? tsum[t - off] : 0;
        __syncthreads();
        tsum[t] += add;
        __syncthreads();
    }
    int ebase = tsum[t] - s0;
#pragma unroll
    for (int k = 0; k < 4; k++) base[t * 4 + k] = ebase + loc[k];
    __syncthreads();
    for (int j = t; j < BSZ; j += 256) {
        int d = d0 + j;
        if (d < D) rowptr[d] = roff + base[j];
    }
    if (b == 0 && t == 0) rowptr[D] = NP;
    if (b == 0 && t < 8) ci[NP + t] = 0;  // zero pad: clamped prefetch beyond NP is safe
    for (int j = t; j < BSZ; j += 256) hist[j] = base[j];
    __syncthreads();
    for (int i = t; i < cnt; i += 256) {
        int2 pr = pairs[roff + i];
        int pos = roff + atomicAdd(&hist[pr.x - d0], 1);
        ci[pos] = pr.y;
    }
}

// =====================================================================
// fused conv, ROW-parallel gather (no LDS atomics, no min-buffer, 1 barrier):
//   each half-wave (32 lanes) owns 4 dst rows; per row it loads up to 8
//   clamped src indices (independent), issues 8 independent 256B row
//   gathers, and reduces with an in-register fmin tree. Next row's / next
//   chunk's indices prefetch under the current gathers. mx written straight
//   to the bf16 h tile in LDS; single barrier; then MFMA MLP + residual.
// =====================================================================

template <bool OUT_F32>
__global__ __launch_bounds__(256) void fused_conv_rp(
    const unsigned short* __restrict__ xsb, const unsigned short* __restrict__ xdb,
    unsigned short* __restrict__ out_b, float* __restrict__ out_f,
    const int* __restrict__ rowptr, const int* __restrict__ ci,
    const unsigned short* __restrict__ Wt, const float* __restrict__ bias, int n_dst) {
    __shared__ unsigned short h[ROWS * 264];  // [32 rows][256 + 8 pad] bf16
    int t = threadIdx.x;
    int wave = t >> 6, lane = t & 63;
    int li = lane & 31, halfIdx = t >> 5;
    int r0 = blockIdx.x * ROWS;
    int rbase = halfIdx * 4;
    const ushort4* xs4 = (const ushort4*)xsb;

    ushort4 xdu[4];
    int startv[4], degv[4];
#pragma unroll
    for (int rr = 0; rr < 4; rr++) {
        int d = r0 + rbase + rr;
        xdu[rr] = make_ushort4(0, 0, 0, 0);
        startv[rr] = 0; degv[rr] = 0;
        if (d < n_dst) {
            xdu[rr] = ((const ushort4*)xdb)[(size_t)d * 32 + li];
            startv[rr] = rowptr[d];
            degv[rr] = rowptr[d + 1] - startv[rr];
        }
    }
    // prefetch row 0 chunk 0 indices (clamped to deg-1; duplicates harmless for min)
    int idx[8];
    {
        int s = startv[0], dgm = degv[0] - 1; if (dgm < 0) dgm = 0;
#pragma unroll
        for (int k = 0; k < 8; k++) { int o = k > dgm ? dgm : k; idx[k] = ci[s + o]; }
    }

#pragma unroll
    for (int rr = 0; rr < 4; rr++) {
        int dg = degv[rr];
        int dgm = dg - 1; if (dgm < 0) dgm = 0;
        float4 mn = make_float4(1e30f, 1e30f, 1e30f, 1e30f);
        int c = 0;
        for (;;) {
            // 8 independent row gathers
            ushort4 u0 = xs4[(size_t)idx[0] * 32 + li];
            ushort4 u1 = xs4[(size_t)idx[1] * 32 + li];
            ushort4 u2 = xs4[(size_t)idx[2] * 32 + li];
            ushort4 u3 = xs4[(size_t)idx[3] * 32 + li];
            ushort4 u4 = xs4[(size_t)idx[4] * 32 + li];
            ushort4 u5 = xs4[(size_t)idx[5] * 32 + li];
            ushort4 u6 = xs4[(size_t)idx[6] * 32 + li];
            ushort4 u7 = xs4[(size_t)idx[7] * 32 + li];
            int cN = c + 8;
            bool more = cN < dg;
            int idxN[8];
            if (more) {  // next chunk of same row
#pragma unroll
                for (int k = 0; k < 8; k++) {
                    int o = cN + k; o = o > dgm ? dgm : o;
                    idxN[k] = ci[startv[rr] + o];
                }
            } else if (rr < 3) {  // first chunk of next row (static rr+1)
                int s2 = startv[rr + 1], dgm2 = degv[rr + 1] - 1; if (dgm2 < 0) dgm2 = 0;
#pragma unroll
                for (int k = 0; k < 8; k++) { int o = k > dgm2 ? dgm2 : k; idxN[k] = ci[s2 + o]; }
            } else {
#pragma unroll
                for (int k = 0; k < 8; k++) idxN[k] = 0;
            }
            mn = fmin4(mn, fmin4(fmin4(bf4_to_f4(u0), bf4_to_f4(u1)),
                                 fmin4(bf4_to_f4(u2), bf4_to_f4(u3))));
            mn = fmin4(mn, fmin4(fmin4(bf4_to_f4(u4), bf4_to_f4(u5)),
                                 fmin4(bf4_to_f4(u6), bf4_to_f4(u7))));
#pragma unroll
            for (int k = 0; k < 8; k++) idx[k] = idxN[k];
            if (!more) break;
            c = cN;
        }
        float4 xdv = bf4_to_f4(xdu[rr]);
        float4 mx;
        mx.x = dg > 0 ? xdv.x - mn.x : 0.f;
        mx.y = dg > 0 ? xdv.y - mn.y : 0.f;
        mx.z = dg > 0 ? xdv.z - mn.z : 0.f;
        mx.w = dg > 0 ? xdv.w - mn.w : 0.f;
        int r = rbase + rr;
        *(ushort4*)&h[r * 264 + 4 * li] = xdu[rr];
        *(ushort4*)&h[r * 264 + 128 + 4 * li] = f4_to_bf4(mx);
    }
    __syncthreads();

    // --- MFMA MLP + residual epilogue
    int rt = wave >> 1;
    int ctbase = (wave & 1) * 4;
    int m = lane & 15, q = lane >> 4;
    f32x4 acc[4];
#pragma unroll
    for (int ct = 0; ct < 4; ct++) acc[ct] = (f32x4){0.f, 0.f, 0.f, 0.f};
    for (int k0 = 0; k0 < 256; k0 += 32) {
        bf16x8 a = *(const bf16x8*)&h[(rt * 16 + m) * 264 + k0 + q * 8];
#pragma unroll
        for (int ct = 0; ct < 4; ct++) {
            int n = (ctbase + ct) * 16 + m;
            bf16x8 b = *(const bf16x8*)&Wt[n * 256 + k0 + q * 8];
            acc[ct] = __builtin_amdgcn_mfma_f32_16x16x32_bf16(a, b, acc[ct], 0, 0, 0);
        }
    }
#pragma unroll
    for (int ct = 0; ct < 4; ct++) {
        int col = (ctbase + ct) * 16 + m;
        float bc = bias[col];
#pragma unroll
        for (int reg = 0; reg < 4; reg++) {
            int r_l = rt * 16 + q * 4 + reg;
            int row = r0 + r_l;
            if (row < n_dst) {
                float xold = bfu(h[r_l * 264 + col]);
                float val = xold + lrelu(acc[ct][reg] + bc);
                if (OUT_F32) out_f[(size_t)row * W + col] = val;
                else out_b[(size_t)row * W + col] = f2bf(val);
            }
        }
    }
}

// ---- v2e variant: src row = on-the-fly vertex embed (deg mean 2 -> chunk 4) ----
__global__ __launch_bounds__(256) void fused_conv_v2e_rp(
    const float* __restrict__ verts, const float* __restrict__ Wv, const float* __restrict__ bv,
    unsigned short* __restrict__ x_eb, const int* __restrict__ rowptr,
    const int* __restrict__ ci,
    const unsigned short* __restrict__ Wt, const float* __restrict__ bias, int n_dst) {
    __shared__ unsigned short h[ROWS * 264];
    int t = threadIdx.x;
    int wave = t >> 6, lane = t & 63;
    int li = lane & 31, halfIdx = t >> 5;
    int r0 = blockIdx.x * ROWS;
    int rbase = halfIdx * 4;

    float4 wv0 = *(const float4*)&Wv[0 * W + 4 * li];
    float4 wv1 = *(const float4*)&Wv[1 * W + 4 * li];
    float4 wv2 = *(const float4*)&Wv[2 * W + 4 * li];
    float4 bvv = *(const float4*)&bv[4 * li];

    ushort4 xdu[4];
    int startv[4], degv[4];
#pragma unroll
    for (int rr = 0; rr < 4; rr++) {
        int d = r0 + rbase + rr;
        xdu[rr] = make_ushort4(0, 0, 0, 0);
        startv[rr] = 0; degv[rr] = 0;
        if (d < n_dst) {
            xdu[rr] = ((const ushort4*)x_eb)[(size_t)d * 32 + li];
            startv[rr] = rowptr[d];
            degv[rr] = rowptr[d + 1] - startv[rr];
        }
    }
    int idx[4];
    {
        int s = startv[0], dgm = degv[0] - 1; if (dgm < 0) dgm = 0;
#pragma unroll
        for (int k = 0; k < 4; k++) { int o = k > dgm ? dgm : k; idx[k] = ci[s + o]; }
    }

#pragma unroll
    for (int rr = 0; rr < 4; rr++) {
        int dg = degv[rr];
        int dgm = dg - 1; if (dgm < 0) dgm = 0;
        float4 mn = make_float4(1e30f, 1e30f, 1e30f, 1e30f);
        int c = 0;
        for (;;) {
            // 12 independent scalar loads (uniform per half-wave -> broadcast)
            float a00 = verts[3 * idx[0]], a01 = verts[3 * idx[0] + 1], a02 = verts[3 * idx[0] + 2];
            float a10 = verts[3 * idx[1]], a11 = verts[3 * idx[1] + 1], a12 = verts[3 * idx[1] + 2];
            float a20 = verts[3 * idx[2]], a21 = verts[3 * idx[2] + 1], a22 = verts[3 * idx[2] + 2];
            float a30 = verts[3 * idx[3]], a31 = verts[3 * idx[3] + 1], a32 = verts[3 * idx[3] + 2];
            int cN = c + 4;
            bool more = cN < dg;
            int idxN[4];
            if (more) {
#pragma unroll
                for (int k = 0; k < 4; k++) {
                    int o = cN + k; o = o > dgm ? dgm : o;
                    idxN[k] = ci[startv[rr] + o];
                }
            } else if (rr < 3) {
                int s2 = startv[rr + 1], dgm2 = degv[rr + 1] - 1; if (dgm2 < 0) dgm2 = 0;
#pragma unroll
                for (int k = 0; k < 4; k++) { int o = k > dgm2 ? dgm2 : k; idxN[k] = ci[s2 + o]; }
            } else {
#pragma unroll
                for (int k = 0; k < 4; k++) idxN[k] = 0;
            }
            float4 e;
            e.x = lrelu(bvv.x + a00 * wv0.x + a01 * wv1.x + a02 * wv2.x);
            e.y = lrelu(bvv.y + a00 * wv0.y + a01 * wv1.y + a02 * wv2.y);
            e.z = lrelu(bvv.z + a00 * wv0.z + a01 * wv1.z + a02 * wv2.z);
            e.w = lrelu(bvv.w + a00 * wv0.w + a01 * wv1.w + a02 * wv2.w);
            mn = fmin4(mn, e);
            e.x = lrelu(bvv.x + a10 * wv0.x + a11 * wv1.x + a12 * wv2.x);
            e.y = lrelu(bvv.y + a10 * wv0.y + a11 * wv1.y + a12 * wv2.y);
            e.z = lrelu(bvv.z + a10 * wv0.z + a11 * wv1.z + a12 * wv2.z);
            e.w = lrelu(bvv.w + a10 * wv0.w + a11 * wv1.w + a12 * wv2.w);
            mn = fmin4(mn, e);
            e.x = lrelu(bvv.x + a20 * wv0.x + a21 * wv1.x + a22 * wv2.x);
            e.y = lrelu(bvv.y + a20 * wv0.y + a21 * wv1.y + a22 * wv2.y);
            e.z = lrelu(bvv.z + a20 * wv0.z + a21 * wv1.z + a22 * wv2.z);
            e.w = lrelu(bvv.w + a20 * wv0.w + a21 * wv1.w + a22 * wv2.w);
            mn = fmin4(mn, e);
            e.x = lrelu(bvv.x + a30 * wv0.x + a31 * wv1.x + a32 * wv2.x);
            e.y = lrelu(bvv.y + a30 * wv0.y + a31 * wv1.y + a32 * wv2.y);
            e.z = lrelu(bvv.z + a30 * wv0.z + a31 * wv1.z + a32 * wv2.z);
            e.w = lrelu(bvv.w + a30 * wv0.w + a31 * wv1.w + a32 * wv2.w);
            mn = fmin4(mn, e);
#pragma unroll
            for (int k = 0; k < 4; k++) idx[k] = idxN[k];
            if (!more) break;
            c = cN;
        }
        float4 xdv = bf4_to_f4(xdu[rr]);
        float4 mx;
        mx.x = dg > 0 ? xdv.x - mn.x : 0.f;
        mx.y = dg > 0 ? xdv.y - mn.y : 0.f;
        mx.z = dg > 0 ? xdv.z - mn.z : 0.f;
        mx.w = dg > 0 ? xdv.w - mn.w : 0.f;
        int r = rbase + rr;
        *(ushort4*)&h[r * 264 + 4 * li] = xdu[rr];
        *(ushort4*)&h[r * 264 + 128 + 4 * li] = f4_to_bf4(mx);
    }
    __syncthreads();

    int rt = wave >> 1;
    int ctbase = (wave & 1) * 4;
    int m = lane & 15, q = lane >> 4;
    f32x4 acc[4];
#pragma unroll
    for (int ct = 0; ct < 4; ct++) acc[ct] = (f32x4){0.f, 0.f, 0.f, 0.f};
    for (int k0 = 0; k0 < 256; k0 += 32) {
        bf16x8 a = *(const bf16x8*)&h[(rt * 16 + m) * 264 + k0 + q * 8];
#pragma unroll
        for (int ct = 0; ct < 4; ct++) {
            int n = (ctbase + ct) * 16 + m;
            bf16x8 b = *(const bf16x8*)&Wt[n * 256 + k0 + q * 8];
            acc[ct] = __builtin_amdgcn_mfma_f32_16x16x32_bf16(a, b, acc[ct], 0, 0, 0);
        }
    }
#pragma unroll
    for (int ct = 0; ct < 4; ct++) {
        int col = (ctbase + ct) * 16 + m;
        float bc = bias[col];
#pragma unroll
        for (int reg = 0; reg < 4; reg++) {
            int r_l = rt * 16 + q * 4 + reg;
            int row = r0 + r_l;
            if (row < n_dst) {
                float xold = bfu(h[r_l * 264 + col]);
                x_eb[(size_t)row * W + col] = f2bf(xold + lrelu(acc[ct][reg] + bc));
            }
        }
    }
}

static inline char* alignp(char* p, size_t a) {
    return (char*)(((uintptr_t)p + a - 1) & ~(uintptr_t)(a - 1));
}

extern "C" void kernel_launch(void* const* d_in, const int* in_sizes, int n_in,
                              void* d_out, int out_size, void* d_ws, size_t ws_size,
                              hipStream_t stream) {
    const float* vertices = (const float*)d_in[0];
    const float* edges    = (const float*)d_in[1];
    const float* faces    = (const float*)d_in[2];
    const int* etv_v   = (const int*)d_in[3];
    const int* etv_e   = (const int*)d_in[4];
    const int* fte_e   = (const int*)d_in[5];
    const int* fte_f   = (const int*)d_in[6];
    const int* ftf_src = (const int*)d_in[7];
    const int* ftf_dst = (const int*)d_in[8];
    const float* Wv   = (const float*)d_in[9];
    const float* bv   = (const float*)d_in[10];
    const float* We   = (const float*)d_in[11];
    const float* be   = (const float*)d_in[12];
    const float* Wf   = (const float*)d_in[13];
    const float* bf_  = (const float*)d_in[14];
    const float* Wv2e = (const float*)d_in[15];
    const float* bv2e = (const float*)d_in[16];
    const float* We2f = (const float*)d_in[17];
    const float* be2f = (const float*)d_in[18];
    const float* Wm0  = (const float*)d_in[19];
    const float* bm0  = (const float*)d_in[20];
    const float* Wm1  = (const float*)d_in[21];
    const float* bm1  = (const float*)d_in[22];

    const int NV = in_sizes[0] / 3;
    const int NE = in_sizes[1] / 12;
    const int NF = in_sizes[2] / 14;
    const int N_EV = in_sizes[3];
    const int N_FE = in_sizes[5];
    const int N_FF = in_sizes[7];
    (void)NV; (void)n_in; (void)out_size; (void)ws_size;

    const int D = NE + NF + NF;
    const int NP = N_EV + N_FE + N_FF;
    const int NB = (D + BSZ - 1) >> BSHIFT;

    // ---- ws layout ----
    char* p = (char*)d_ws;
    unsigned short* x_eb = (unsigned short*)p;  p += (size_t)NE * W * sizeof(unsigned short);
    unsigned short* f0b  = (unsigned short*)p;  p += (size_t)NF * W * sizeof(unsigned short);
    unsigned short* f1b  = (unsigned short*)p;  p += (size_t)NF * W * sizeof(unsigned short);
    p = alignp(p, 16);
    int2* pairs = (int2*)p;                     p += (size_t)NP * sizeof(int2);
    int* ci     = (int*)p;                      p += (size_t)(NP + 8) * sizeof(int);
    int* rowptr = (int*)p;                      p += (size_t)(D + 1) * sizeof(int);
    int* gcnt   = (int*)p;                      p += 512 * sizeof(int);
    int* goff   = (int*)p;                      p += 513 * sizeof(int);
    int* gcur   = (int*)p;                      p += 512 * sizeof(int);
    p = alignp(p, 16);
    unsigned short* Wt0 = (unsigned short*)p;   p += (size_t)32768 * sizeof(unsigned short);
    unsigned short* Wt1 = (unsigned short*)p;   p += (size_t)32768 * sizeof(unsigned short);
    unsigned short* Wt2 = (unsigned short*)p;   p += (size_t)32768 * sizeof(unsigned short);
    unsigned short* Wt3 = (unsigned short*)p;   p += (size_t)32768 * sizeof(unsigned short);

    float* out_f = (float*)d_out;
    const int TB = 256;

    // ---- embeds (bf16); x_v folded into conv1 ----
    embed_kernel<12><<<((size_t)NE * W + TB - 1) / TB, TB, 0, stream>>>(edges, We, be, x_eb, NE);
    embed_kernel<14><<<((size_t)NF * W + TB - 1) / TB, TB, 0, stream>>>(faces, Wf, bf_, f0b, NF);
    wconv4_kernel<<<512, TB, 0, stream>>>(Wv2e, We2f, Wm0, Wm1, Wt0, Wt1, Wt2, Wt3);

    // ---- bucket-partitioned CSR build ----
    PairSrc P = {etv_e, etv_v, N_EV, fte_f, fte_e, N_FE, ftf_dst, ftf_src, N_FF, NE, NF};
    (void)hipMemsetAsync(gcnt, 0, 512 * sizeof(int), stream);
    int ablocks = (NP + CHUNK - 1) / CHUNK;
    part_hist<<<ablocks, TB, 0, stream>>>(P, gcnt);
    bucket_scan<<<1, 512, 0, stream>>>(gcnt, goff, gcur, NB, NP);
    part_scatter<<<ablocks, TB, 0, stream>>>(P, gcur, pairs);
    bucket_sort<<<NB, TB, 0, stream>>>(pairs, goff, D, NP, rowptr, ci);

    // ---- fused convs (row-parallel in-register gather-min) ----
    fused_conv_v2e_rp<<<(NE + ROWS - 1) / ROWS, TB, 0, stream>>>(vertices, Wv, bv, x_eb, rowptr,
                                                                 ci, Wt0, bv2e, NE);
    fused_conv_rp<false><<<(NF + ROWS - 1) / ROWS, TB, 0, stream>>>(
        x_eb, f0b, f0b, nullptr, rowptr + NE, ci, Wt1, be2f, NF);
    fused_conv_rp<false><<<(NF + ROWS - 1) / ROWS, TB, 0, stream>>>(
        f0b, f0b, f1b, nullptr, rowptr + NE + NF, ci, Wt2, bm0, NF);
    fused_conv_rp<true><<<(NF + ROWS - 1) / ROWS, TB, 0, stream>>>(
        f1b, f1b, nullptr, out_f, rowptr + NE + NF, ci, Wt3, bm1, NF);
}

// Round 3
// 739.771 us; speedup vs baseline: 1.0182x; 1.0114x over previous
//
#include <hip/hip_runtime.h>

#define W 128
#define ROWS 32      // dst rows per block in fused_conv
#define BSHIFT 10    // 1024 dst ids per bucket
#define BSZ 1024

typedef short bf16x8 __attribute__((ext_vector_type(8)));
typedef float f32x4 __attribute__((ext_vector_type(4)));

__device__ __forceinline__ float lrelu(float x) { return x > 0.f ? x : 0.01f * x; }

// RTNE float -> bf16 (as ushort bit pattern)
__device__ __forceinline__ unsigned short f2bf(float f) {
    unsigned u = __float_as_uint(f);
    u += 0x7fffu + ((u >> 16) & 1u);
    return (unsigned short)(u >> 16);
}
__device__ __forceinline__ float bfu(unsigned short u) {
    return __uint_as_float(((unsigned)u) << 16);
}
// dword-level bf16 pair unpack: 1 VALU per channel
__device__ __forceinline__ float lo16(unsigned u) { return __uint_as_float(u << 16); }
__device__ __forceinline__ float hi16(unsigned u) { return __uint_as_float(u & 0xffff0000u); }
__device__ __forceinline__ unsigned pack2bf(float lo, float hi) {
    return (unsigned)f2bf(lo) | ((unsigned)f2bf(hi) << 16);
}
// unpack 8 bf16 channels from uint4 and min-accumulate
__device__ __forceinline__ void upmin8(float* mn, uint4 u) {
    mn[0] = fminf(mn[0], lo16(u.x)); mn[1] = fminf(mn[1], hi16(u.x));
    mn[2] = fminf(mn[2], lo16(u.y)); mn[3] = fminf(mn[3], hi16(u.y));
    mn[4] = fminf(mn[4], lo16(u.z)); mn[5] = fminf(mn[5], hi16(u.z));
    mn[6] = fminf(mn[6], lo16(u.w)); mn[7] = fminf(mn[7], hi16(u.w));
}

// ---- initial embed: lrelu(in @ Wm + b) -> bf16 ----
template <int K>
__global__ void embed_kernel(const float* __restrict__ in, const float* __restrict__ Wm,
                             const float* __restrict__ bias, unsigned short* __restrict__ outb,
                             int n) {
    int t = blockIdx.x * 256 + threadIdx.x;
    int row = t >> 7, c = t & 127;
    if (row >= n) return;
    float s = bias[c];
#pragma unroll
    for (int k = 0; k < K; k++) s += in[row * K + k] * Wm[k * W + c];
    outb[(size_t)row * W + c] = f2bf(lrelu(s));
}

// ---- fused weight convert: 4x [256][128] fp32 -> [128][256] bf16 transposed ----
__global__ void wconv4_kernel(const float* __restrict__ W0, const float* __restrict__ W1,
                              const float* __restrict__ W2, const float* __restrict__ W3,
                              unsigned short* __restrict__ T0, unsigned short* __restrict__ T1,
                              unsigned short* __restrict__ T2, unsigned short* __restrict__ T3) {
    int which = blockIdx.x >> 7;
    const float* Wm = (which == 0) ? W0 : (which == 1) ? W1 : (which == 2) ? W2 : W3;
    unsigned short* Wt = (which == 0) ? T0 : (which == 1) ? T1 : (which == 2) ? T2 : T3;
    int i = (blockIdx.x & 127) * 256 + threadIdx.x;  // 32768 per matrix
    int k = i >> 7, n = i & 127;
    Wt[n * 256 + k] = f2bf(Wm[k * W + n]);
}

// ---- bucket-partitioned CSR build over concatenated dst domain ----
struct PairSrc {
    const int* d0; const int* s0; int n0;
    const int* d1; const int* s1; int n1;
    const int* d2; const int* s2; int n2;
    int NE, NF;
};

__device__ __forceinline__ void pair_at(const PairSrc& P, int g, int& dp, int& sp) {
    dp = -1; sp = 0;
    if (g < P.n0) { dp = P.d0[g]; sp = P.s0[g]; }
    else if (g < P.n0 + P.n1) { int j = g - P.n0; dp = P.NE + P.d1[j]; sp = P.s1[j]; }
    else if (g < P.n0 + P.n1 + P.n2) { int j = g - P.n0 - P.n1; dp = P.NE + P.NF + P.d2[j]; sp = P.s2[j]; }
}

#define CHUNK 4096

__global__ __launch_bounds__(256) void part_hist(PairSrc P, int* __restrict__ gcnt) {
    __shared__ int hist[512];
    int t = threadIdx.x;
    for (int j = t; j < 512; j += 256) hist[j] = 0;
    __syncthreads();
    int g0 = blockIdx.x * CHUNK;
#pragma unroll
    for (int k = 0; k < 16; k++) {
        int dp, sp;
        pair_at(P, g0 + k * 256 + t, dp, sp);
        if (dp >= 0) atomicAdd(&hist[dp >> BSHIFT], 1);
    }
    __syncthreads();
    for (int j = t; j < 512; j += 256)
        if (hist[j]) atomicAdd(&gcnt[j], hist[j]);
}

__global__ void bucket_scan(const int* __restrict__ gcnt, int* __restrict__ goff,
                            int* __restrict__ gcur, int NB, int NP) {
    __shared__ int s[512];
    int t = threadIdx.x;
    int v = (t < NB) ? gcnt[t] : 0;
    s[t] = v;
    __syncthreads();
    for (int off = 1; off < 512; off <<= 1) {
        int add = (t >= off) ? s[t - off] : 0;
        __syncthreads();
        s[t] += add;
        __syncthreads();
    }
    if (t < NB) {
        int excl = s[t] - v;
        goff[t] = excl;
        gcur[t] = excl;
    }
    if (t == 0) goff[NB] = NP;
}

__global__ __launch_bounds__(256) void part_scatter(PairSrc P, int* __restrict__ gcur,
                                                    int2* __restrict__ pairs) {
    __shared__ int hist[512];
    __shared__ int base[512];
    int t = threadIdx.x;
    for (int j = t; j < 512; j += 256) hist[j] = 0;
    __syncthreads();
    int g0 = blockIdx.x * CHUNK;
    int dv[16], sv[16], rk[16];
#pragma unroll
    for (int k = 0; k < 16; k++) {
        pair_at(P, g0 + k * 256 + t, dv[k], sv[k]);
        rk[k] = (dv[k] >= 0) ? atomicAdd(&hist[dv[k] >> BSHIFT], 1) : 0;
    }
    __syncthreads();
    for (int j = t; j < 512; j += 256)
        base[j] = hist[j] ? atomicAdd(&gcur[j], hist[j]) : 0;
    __syncthreads();
#pragma unroll
    for (int k = 0; k < 16; k++) {
        if (dv[k] >= 0) pairs[base[dv[k] >> BSHIFT] + rk[k]] = make_int2(dv[k], sv[k]);
    }
}

// one block per bucket: LDS counting sort -> rowptr + ci (src only; dst is
// implicit from rowptr segmentation in the row-parallel conv)
__global__ __launch_bounds__(256) void bucket_sort(const int2* __restrict__ pairs,
                                                   const int* __restrict__ goff, int D, int NP,
                                                   int* __restrict__ rowptr,
                                                   int* __restrict__ ci) {
    __shared__ int hist[BSZ];
    __shared__ int base[BSZ];
    __shared__ int tsum[256];
    int b = blockIdx.x, t = threadIdx.x;
    int d0 = b << BSHIFT;
    int roff = goff[b], rend = goff[b + 1], cnt = rend - roff;
    for (int j = t; j < BSZ; j += 256) hist[j] = 0;
    __syncthreads();
    for (int i = t; i < cnt; i += 256) {
        int2 pr = pairs[roff + i];
        atomicAdd(&hist[pr.x - d0], 1);
    }
    __syncthreads();
    int loc[4], s0 = 0;
#pragma unroll
    for (int k = 0; k < 4; k++) {
        loc[k] = s0;
        s0 += hist[t * 4 + k];
    }
    tsum[t] = s0;
    __syncthreads();
    for (int off = 1; off < 256; off <<= 1) {
        int add = (t >= off) ? tsum[t - off] : 0;
        __syncthreads();
        tsum[t] += add;
        __syncthreads();
    }
    int ebase = tsum[t] - s0;
#pragma unroll
    for (int k = 0; k < 4; k++) base[t * 4 + k] = ebase + loc[k];
    __syncthreads();
    for (int j = t; j < BSZ; j += 256) {
        int d = d0 + j;
        if (d < D) rowptr[d] = roff + base[j];
    }
    if (b == 0 && t == 0) rowptr[D] = NP;
    if (b == 0 && t < 8) ci[NP + t] = 0;  // zero pad: clamped prefetch beyond NP is safe
    for (int j = t; j < BSZ; j += 256) hist[j] = base[j];
    __syncthreads();
    for (int i = t; i < cnt; i += 256) {
        int2 pr = pairs[roff + i];
        int pos = roff + atomicAdd(&hist[pr.x - d0], 1);
        ci[pos] = pr.y;
    }
}

// =====================================================================
// fused conv, ROW-parallel gather, 16B-lane edition:
//   each half-wave (32 lanes) owns 4 dst rows. Rows are 256B; a lane
//   covers 8 channels (16B uint4 = 8 bf16). The half-wave splits into
//   two pair-groups g=0/1, so each gather instruction serves 2 pairs
//   (4 per wave). Per chunk: 4 gather instrs (8 pairs) + dword-level
//   unpack (1 VALU/channel) + fmin; next chunk / next row indices
//   prefetched under the gathers. Row min combined across g with one
//   shfl_xor(16). mx written straight to bf16 h tile; single barrier;
//   MFMA MLP + residual epilogue.
// =====================================================================

template <bool OUT_F32>
__global__ __launch_bounds__(256) void fused_conv_rp(
    const unsigned short* __restrict__ xsb, const unsigned short* __restrict__ xdb,
    unsigned short* __restrict__ out_b, float* __restrict__ out_f,
    const int* __restrict__ rowptr, const int* __restrict__ ci,
    const unsigned short* __restrict__ Wt, const float* __restrict__ bias, int n_dst) {
    __shared__ unsigned short h[ROWS * 264];  // [32 rows][256 + 8 pad] bf16
    int t = threadIdx.x;
    int wave = t >> 6, lane = t & 63;
    int halfIdx = t >> 5;
    int li16 = lane & 15;       // position within 256B row
    int g = (lane >> 4) & 1;    // pair-group within half-wave
    int r0 = blockIdx.x * ROWS;
    int rbase = halfIdx * 4;
    const uint4* xs4 = (const uint4*)xsb;
    const uint4* xd4 = (const uint4*)xdb;

    int startv[4], degv[4];
#pragma unroll
    for (int rr = 0; rr < 4; rr++) {
        int d = r0 + rbase + rr;
        startv[rr] = 0; degv[rr] = 0;
        if (d < n_dst) {
            startv[rr] = rowptr[d];
            degv[rr] = rowptr[d + 1] - startv[rr];
        }
    }
    // prefetch row 0 chunk 0 indices (clamped; duplicates harmless for min)
    int idx[4];
    {
        int s = startv[0], dgm = degv[0] - 1; if (dgm < 0) dgm = 0;
#pragma unroll
        for (int j = 0; j < 4; j++) { int o = 2 * j + g; o = o > dgm ? dgm : o; idx[j] = ci[s + o]; }
    }

#pragma unroll
    for (int rr = 0; rr < 4; rr++) {
        int d = r0 + rbase + rr;
        uint4 xdv = make_uint4(0, 0, 0, 0);
        if (d < n_dst) xdv = xd4[(size_t)d * 16 + li16];  // own row, hidden under gathers
        int dg = degv[rr];
        int dgm = dg - 1; if (dgm < 0) dgm = 0;
        float mn[8];
#pragma unroll
        for (int k = 0; k < 8; k++) mn[k] = 1e30f;
        int c = 0;
        for (;;) {
            // 4 independent gathers (this lane's 2-pair share of an 8-pair chunk)
            uint4 u0 = xs4[(size_t)idx[0] * 16 + li16];
            uint4 u1 = xs4[(size_t)idx[1] * 16 + li16];
            uint4 u2 = xs4[(size_t)idx[2] * 16 + li16];
            uint4 u3 = xs4[(size_t)idx[3] * 16 + li16];
            int cN = c + 8;
            bool more = cN < dg;
            int idxN[4];
            if (more) {  // next chunk of same row
#pragma unroll
                for (int j = 0; j < 4; j++) {
                    int o = cN + 2 * j + g; o = o > dgm ? dgm : o;
                    idxN[j] = ci[startv[rr] + o];
                }
            } else if (rr < 3) {  // first chunk of next row (static rr+1)
                int s2 = startv[rr + 1], dgm2 = degv[rr + 1] - 1; if (dgm2 < 0) dgm2 = 0;
#pragma unroll
                for (int j = 0; j < 4; j++) { int o = 2 * j + g; o = o > dgm2 ? dgm2 : o; idxN[j] = ci[s2 + o]; }
            } else {
#pragma unroll
                for (int j = 0; j < 4; j++) idxN[j] = 0;
            }
            upmin8(mn, u0); upmin8(mn, u1); upmin8(mn, u2); upmin8(mn, u3);
#pragma unroll
            for (int j = 0; j < 4; j++) idx[j] = idxN[j];
            if (!more) break;
            c = cN;
        }
        // combine the two pair-groups of this half-wave
#pragma unroll
        for (int k = 0; k < 8; k++) mn[k] = fminf(mn[k], __shfl_xor(mn[k], 16));
        // mx = deg ? xd - mn : 0 ; pack to bf16
        float m0 = dg ? lo16(xdv.x) - mn[0] : 0.f;
        float m1 = dg ? hi16(xdv.x) - mn[1] : 0.f;
        float m2 = dg ? lo16(xdv.y) - mn[2] : 0.f;
        float m3 = dg ? hi16(xdv.y) - mn[3] : 0.f;
        float m4 = dg ? lo16(xdv.z) - mn[4] : 0.f;
        float m5 = dg ? hi16(xdv.z) - mn[5] : 0.f;
        float m6 = dg ? lo16(xdv.w) - mn[6] : 0.f;
        float m7 = dg ? hi16(xdv.w) - mn[7] : 0.f;
        uint4 mxp = make_uint4(pack2bf(m0, m1), pack2bf(m2, m3), pack2bf(m4, m5), pack2bf(m6, m7));
        int r = rbase + rr;
        // both g groups write identical data (benign dup)
        *(uint4*)&h[r * 264 + li16 * 8] = xdv;
        *(uint4*)&h[r * 264 + 128 + li16 * 8] = mxp;
    }
    __syncthreads();

    // --- MFMA MLP + residual epilogue
    int rt = wave >> 1;
    int ctbase = (wave & 1) * 4;
    int m = lane & 15, q = lane >> 4;
    f32x4 acc[4];
#pragma unroll
    for (int ct = 0; ct < 4; ct++) acc[ct] = (f32x4){0.f, 0.f, 0.f, 0.f};
    for (int k0 = 0; k0 < 256; k0 += 32) {
        bf16x8 a = *(const bf16x8*)&h[(rt * 16 + m) * 264 + k0 + q * 8];
#pragma unroll
        for (int ct = 0; ct < 4; ct++) {
            int n = (ctbase + ct) * 16 + m;
            bf16x8 b = *(const bf16x8*)&Wt[n * 256 + k0 + q * 8];
            acc[ct] = __builtin_amdgcn_mfma_f32_16x16x32_bf16(a, b, acc[ct], 0, 0, 0);
        }
    }
#pragma unroll
    for (int ct = 0; ct < 4; ct++) {
        int col = (ctbase + ct) * 16 + m;
        float bc = bias[col];
#pragma unroll
        for (int reg = 0; reg < 4; reg++) {
            int r_l = rt * 16 + q * 4 + reg;
            int row = r0 + r_l;
            if (row < n_dst) {
                float xold = bfu(h[r_l * 264 + col]);
                float val = xold + lrelu(acc[ct][reg] + bc);
                if (OUT_F32) out_f[(size_t)row * W + col] = val;
                else out_b[(size_t)row * W + col] = f2bf(val);
            }
        }
    }
}

static inline char* alignp(char* p, size_t a) {
    return (char*)(((uintptr_t)p + a - 1) & ~(uintptr_t)(a - 1));
}

extern "C" void kernel_launch(void* const* d_in, const int* in_sizes, int n_in,
                              void* d_out, int out_size, void* d_ws, size_t ws_size,
                              hipStream_t stream) {
    const float* vertices = (const float*)d_in[0];
    const float* edges    = (const float*)d_in[1];
    const float* faces    = (const float*)d_in[2];
    const int* etv_v   = (const int*)d_in[3];
    const int* etv_e   = (const int*)d_in[4];
    const int* fte_e   = (const int*)d_in[5];
    const int* fte_f   = (const int*)d_in[6];
    const int* ftf_src = (const int*)d_in[7];
    const int* ftf_dst = (const int*)d_in[8];
    const float* Wv   = (const float*)d_in[9];
    const float* bv   = (const float*)d_in[10];
    const float* We   = (const float*)d_in[11];
    const float* be   = (const float*)d_in[12];
    const float* Wf   = (const float*)d_in[13];
    const float* bf_  = (const float*)d_in[14];
    const float* Wv2e = (const float*)d_in[15];
    const float* bv2e = (const float*)d_in[16];
    const float* We2f = (const float*)d_in[17];
    const float* be2f = (const float*)d_in[18];
    const float* Wm0  = (const float*)d_in[19];
    const float* bm0  = (const float*)d_in[20];
    const float* Wm1  = (const float*)d_in[21];
    const float* bm1  = (const float*)d_in[22];

    const int NV = in_sizes[0] / 3;
    const int NE = in_sizes[1] / 12;
    const int NF = in_sizes[2] / 14;
    const int N_EV = in_sizes[3];
    const int N_FE = in_sizes[5];
    const int N_FF = in_sizes[7];
    (void)n_in; (void)out_size; (void)ws_size;

    const int D = NE + NF + NF;
    const int NP = N_EV + N_FE + N_FF;
    const int NB = (D + BSZ - 1) >> BSHIFT;

    // ---- ws layout ----
    char* p = (char*)d_ws;
    unsigned short* x_eb = (unsigned short*)p;  p += (size_t)NE * W * sizeof(unsigned short);
    unsigned short* f0b  = (unsigned short*)p;  p += (size_t)NF * W * sizeof(unsigned short);
    unsigned short* f1b  = (unsigned short*)p;  p += (size_t)(NF > NV ? NF : NV) * W * sizeof(unsigned short);
    p = alignp(p, 16);
    int2* pairs = (int2*)p;                     p += (size_t)NP * sizeof(int2);
    int* ci     = (int*)p;                      p += (size_t)(NP + 8) * sizeof(int);
    int* rowptr = (int*)p;                      p += (size_t)(D + 1) * sizeof(int);
    int* gcnt   = (int*)p;                      p += 512 * sizeof(int);
    int* goff   = (int*)p;                      p += 513 * sizeof(int);
    int* gcur   = (int*)p;                      p += 512 * sizeof(int);
    p = alignp(p, 16);
    unsigned short* Wt0 = (unsigned short*)p;   p += (size_t)32768 * sizeof(unsigned short);
    unsigned short* Wt1 = (unsigned short*)p;   p += (size_t)32768 * sizeof(unsigned short);
    unsigned short* Wt2 = (unsigned short*)p;   p += (size_t)32768 * sizeof(unsigned short);
    unsigned short* Wt3 = (unsigned short*)p;   p += (size_t)32768 * sizeof(unsigned short);

    // x_v bf16 embed aliases f1b: x_vb is dead after the V2E conv, and f1b is
    // first written by conv m0 (two convs later on the same stream). NV==NF
    // here but the region is sized max(NF,NV) above to be safe.
    unsigned short* x_vb = f1b;

    float* out_f = (float*)d_out;
    const int TB = 256;

    // ---- embeds (bf16); x_v now precomputed once instead of per-edge ----
    embed_kernel<3><<<((size_t)NV * W + TB - 1) / TB, TB, 0, stream>>>(vertices, Wv, bv, x_vb, NV);
    embed_kernel<12><<<((size_t)NE * W + TB - 1) / TB, TB, 0, stream>>>(edges, We, be, x_eb, NE);
    embed_kernel<14><<<((size_t)NF * W + TB - 1) / TB, TB, 0, stream>>>(faces, Wf, bf_, f0b, NF);
    wconv4_kernel<<<512, TB, 0, stream>>>(Wv2e, We2f, Wm0, Wm1, Wt0, Wt1, Wt2, Wt3);

    // ---- bucket-partitioned CSR build ----
    PairSrc P = {etv_e, etv_v, N_EV, fte_f, fte_e, N_FE, ftf_dst, ftf_src, N_FF, NE, NF};
    (void)hipMemsetAsync(gcnt, 0, 512 * sizeof(int), stream);
    int ablocks = (NP + CHUNK - 1) / CHUNK;
    part_hist<<<ablocks, TB, 0, stream>>>(P, gcnt);
    bucket_scan<<<1, 512, 0, stream>>>(gcnt, goff, gcur, NB, NP);
    part_scatter<<<ablocks, TB, 0, stream>>>(P, gcur, pairs);
    bucket_sort<<<NB, TB, 0, stream>>>(pairs, goff, D, NP, rowptr, ci);

    // ---- fused convs (row-parallel, 16B-lane gathers) ----
    fused_conv_rp<false><<<(NE + ROWS - 1) / ROWS, TB, 0, stream>>>(
        x_vb, x_eb, x_eb, nullptr, rowptr, ci, Wt0, bv2e, NE);
    fused_conv_rp<false><<<(NF + ROWS - 1) / ROWS, TB, 0, stream>>>(
        x_eb, f0b, f0b, nullptr, rowptr + NE, ci, Wt1, be2f, NF);
    fused_conv_rp<false><<<(NF + ROWS - 1) / ROWS, TB, 0, stream>>>(
        f0b, f0b, f1b, nullptr, rowptr + NE + NF, ci, Wt2, bm0, NF);
    fused_conv_rp<true><<<(NF + ROWS - 1) / ROWS, TB, 0, stream>>>(
        f1b, f1b, nullptr, out_f, rowptr + NE + NF, ci, Wt3, bm1, NF);
}

// Round 4
// 730.867 us; speedup vs baseline: 1.0306x; 1.0122x over previous
//
#include <hip/hip_runtime.h>

#define W 128
#define ROWS 32      // dst rows per block in fused_conv
#define BSHIFT 10    // 1024 dst ids per bucket
#define BSZ 1024

typedef short bf16x8 __attribute__((ext_vector_type(8)));
typedef float f32x4 __attribute__((ext_vector_type(4)));

__device__ __forceinline__ float lrelu(float x) { return x > 0.f ? x : 0.01f * x; }

// RTNE float -> bf16 (as ushort bit pattern)
__device__ __forceinline__ unsigned short f2bf(float f) {
    unsigned u = __float_as_uint(f);
    u += 0x7fffu + ((u >> 16) & 1u);
    return (unsigned short)(u >> 16);
}
__device__ __forceinline__ float bfu(unsigned short u) {
    return __uint_as_float(((unsigned)u) << 16);
}
// dword-level bf16 pair unpack: 1 VALU per channel
__device__ __forceinline__ float lo16(unsigned u) { return __uint_as_float(u << 16); }
__device__ __forceinline__ float hi16(unsigned u) { return __uint_as_float(u & 0xffff0000u); }
__device__ __forceinline__ unsigned pack2bf(float lo, float hi) {
    return (unsigned)f2bf(lo) | ((unsigned)f2bf(hi) << 16);
}
// unpack 8 bf16 channels from uint4 and min-accumulate
__device__ __forceinline__ void upmin8(float* mn, uint4 u) {
    mn[0] = fminf(mn[0], lo16(u.x)); mn[1] = fminf(mn[1], hi16(u.x));
    mn[2] = fminf(mn[2], lo16(u.y)); mn[3] = fminf(mn[3], hi16(u.y));
    mn[4] = fminf(mn[4], lo16(u.z)); mn[5] = fminf(mn[5], hi16(u.z));
    mn[6] = fminf(mn[6], lo16(u.w)); mn[7] = fminf(mn[7], hi16(u.w));
}

// ---- initial embed: lrelu(in @ Wm + b) -> bf16 ----
template <int K>
__global__ void embed_kernel(const float* __restrict__ in, const float* __restrict__ Wm,
                             const float* __restrict__ bias, unsigned short* __restrict__ outb,
                             int n) {
    int t = blockIdx.x * 256 + threadIdx.x;
    int row = t >> 7, c = t & 127;
    if (row >= n) return;
    float s = bias[c];
#pragma unroll
    for (int k = 0; k < K; k++) s += in[row * K + k] * Wm[k * W + c];
    outb[(size_t)row * W + c] = f2bf(lrelu(s));
}

// ---- fused weight convert: 4x [256][128] fp32 -> [128][256] bf16 transposed ----
__global__ void wconv4_kernel(const float* __restrict__ W0, const float* __restrict__ W1,
                              const float* __restrict__ W2, const float* __restrict__ W3,
                              unsigned short* __restrict__ T0, unsigned short* __restrict__ T1,
                              unsigned short* __restrict__ T2, unsigned short* __restrict__ T3) {
    int which = blockIdx.x >> 7;
    const float* Wm = (which == 0) ? W0 : (which == 1) ? W1 : (which == 2) ? W2 : W3;
    unsigned short* Wt = (which == 0) ? T0 : (which == 1) ? T1 : (which == 2) ? T2 : T3;
    int i = (blockIdx.x & 127) * 256 + threadIdx.x;  // 32768 per matrix
    int k = i >> 7, n = i & 127;
    Wt[n * 256 + k] = f2bf(Wm[k * W + n]);
}

// ---- bucket-partitioned CSR build over concatenated dst domain ----
struct PairSrc {
    const int* d0; const int* s0; int n0;
    const int* d1; const int* s1; int n1;
    const int* d2; const int* s2; int n2;
    int NE, NF;
};

__device__ __forceinline__ void pair_at(const PairSrc& P, int g, int& dp, int& sp) {
    dp = -1; sp = 0;
    if (g < P.n0) { dp = P.d0[g]; sp = P.s0[g]; }
    else if (g < P.n0 + P.n1) { int j = g - P.n0; dp = P.NE + P.d1[j]; sp = P.s1[j]; }
    else if (g < P.n0 + P.n1 + P.n2) { int j = g - P.n0 - P.n1; dp = P.NE + P.NF + P.d2[j]; sp = P.s2[j]; }
}

#define CHUNK 4096

__global__ __launch_bounds__(256) void part_hist(PairSrc P, int* __restrict__ gcnt) {
    __shared__ int hist[512];
    int t = threadIdx.x;
    for (int j = t; j < 512; j += 256) hist[j] = 0;
    __syncthreads();
    int g0 = blockIdx.x * CHUNK;
#pragma unroll
    for (int k = 0; k < 16; k++) {
        int dp, sp;
        pair_at(P, g0 + k * 256 + t, dp, sp);
        if (dp >= 0) atomicAdd(&hist[dp >> BSHIFT], 1);
    }
    __syncthreads();
    for (int j = t; j < 512; j += 256)
        if (hist[j]) atomicAdd(&gcnt[j], hist[j]);
}

__global__ void bucket_scan(const int* __restrict__ gcnt, int* __restrict__ goff,
                            int* __restrict__ gcur, int NB, int NP) {
    __shared__ int s[512];
    int t = threadIdx.x;
    int v = (t < NB) ? gcnt[t] : 0;
    s[t] = v;
    __syncthreads();
    for (int off = 1; off < 512; off <<= 1) {
        int add = (t >= off) ? s[t - off] : 0;
        __syncthreads();
        s[t] += add;
        __syncthreads();
    }
    if (t < NB) {
        int excl = s[t] - v;
        goff[t] = excl;
        gcur[t] = excl;
    }
    if (t == 0) goff[NB] = NP;
}

__global__ __launch_bounds__(256) void part_scatter(PairSrc P, int* __restrict__ gcur,
                                                    int2* __restrict__ pairs) {
    __shared__ int hist[512];
    __shared__ int base[512];
    int t = threadIdx.x;
    for (int j = t; j < 512; j += 256) hist[j] = 0;
    __syncthreads();
    int g0 = blockIdx.x * CHUNK;
    int dv[16], sv[16], rk[16];
#pragma unroll
    for (int k = 0; k < 16; k++) {
        pair_at(P, g0 + k * 256 + t, dv[k], sv[k]);
        rk[k] = (dv[k] >= 0) ? atomicAdd(&hist[dv[k] >> BSHIFT], 1) : 0;
    }
    __syncthreads();
    for (int j = t; j < 512; j += 256)
        base[j] = hist[j] ? atomicAdd(&gcur[j], hist[j]) : 0;
    __syncthreads();
#pragma unroll
    for (int k = 0; k < 16; k++) {
        if (dv[k] >= 0) pairs[base[dv[k] >> BSHIFT] + rk[k]] = make_int2(dv[k], sv[k]);
    }
}

// one block per bucket: LDS counting sort -> rowptr + ci (src only; dst is
// implicit from rowptr segmentation in the row-parallel conv)
__global__ __launch_bounds__(256) void bucket_sort(const int2* __restrict__ pairs,
                                                   const int* __restrict__ goff, int D, int NP,
                                                   int* __restrict__ rowptr,
                                                   int* __restrict__ ci) {
    __shared__ int hist[BSZ];
    __shared__ int base[BSZ];
    __shared__ int tsum[256];
    int b = blockIdx.x, t = threadIdx.x;
    int d0 = b << BSHIFT;
    int roff = goff[b], rend = goff[b + 1], cnt = rend - roff;
    for (int j = t; j < BSZ; j += 256) hist[j] = 0;
    __syncthreads();
    for (int i = t; i < cnt; i += 256) {
        int2 pr = pairs[roff + i];
        atomicAdd(&hist[pr.x - d0], 1);
    }
    __syncthreads();
    int loc[4], s0 = 0;
#pragma unroll
    for (int k = 0; k < 4; k++) {
        loc[k] = s0;
        s0 += hist[t * 4 + k];
    }
    tsum[t] = s0;
    __syncthreads();
    for (int off = 1; off < 256; off <<= 1) {
        int add = (t >= off) ? tsum[t - off] : 0;
        __syncthreads();
        tsum[t] += add;
        __syncthreads();
    }
    int ebase = tsum[t] - s0;
#pragma unroll
    for (int k = 0; k < 4; k++) base[t * 4 + k] = ebase + loc[k];
    __syncthreads();
    for (int j = t; j < BSZ; j += 256) {
        int d = d0 + j;
        if (d < D) rowptr[d] = roff + base[j];
    }
    if (b == 0 && t == 0) rowptr[D] = NP;
    if (b == 0 && t < 8) ci[NP + t] = 0;  // zero pad: clamped prefetch beyond NP is safe
    for (int j = t; j < BSZ; j += 256) hist[j] = base[j];
    __syncthreads();
    for (int i = t; i < cnt; i += 256) {
        int2 pr = pairs[roff + i];
        int pos = roff + atomicAdd(&hist[pr.x - d0], 1);
        ci[pos] = pr.y;
    }
}

// =====================================================================
// fused conv, ROW-parallel gather, deep-MLP edition:
//   16 groups of 16 lanes per block; each group owns 2 dst rows. A lane
//   covers 8 channels (16B uint4 = 8 bf16) of every neighbor, so the
//   row-min is lane-local (no cross-lane combine). Per chunk the group
//   issues 8 independent row gathers (8 KB in flight per wave vs 4 KB
//   before) and prefetches next-chunk / next-row indices under them.
//   Serial latency exposures per stream: ~3 (was ~6). mx written straight
//   to the bf16 h tile; single barrier; MFMA MLP + residual epilogue.
// =====================================================================

template <bool OUT_F32>
__global__ __launch_bounds__(256) void fused_conv_rp(
    const unsigned short* __restrict__ xsb, const unsigned short* __restrict__ xdb,
    unsigned short* __restrict__ out_b, float* __restrict__ out_f,
    const int* __restrict__ rowptr, const int* __restrict__ ci,
    const unsigned short* __restrict__ Wt, const float* __restrict__ bias, int n_dst) {
    __shared__ unsigned short h[ROWS * 264];  // [32 rows][256 + 8 pad] bf16
    int t = threadIdx.x;
    int wave = t >> 6, lane = t & 63;
    int grp = t >> 4;        // 0..15, owns rows {2*grp, 2*grp+1}
    int li16 = t & 15;       // 16B slot within 256B row
    int r0 = blockIdx.x * ROWS;
    int rbase = grp * 2;
    const uint4* xs4 = (const uint4*)xsb;
    const uint4* xd4 = (const uint4*)xdb;

    int startv[2], degv[2];
#pragma unroll
    for (int rr = 0; rr < 2; rr++) {
        int d = r0 + rbase + rr;
        startv[rr] = 0; degv[rr] = 0;
        if (d < n_dst) {
            startv[rr] = rowptr[d];
            degv[rr] = rowptr[d + 1] - startv[rr];
        }
    }
    // prefetch row 0 chunk 0 indices (clamped; duplicates harmless for min)
    int idx[8];
    {
        int s = startv[0], dgm = degv[0] - 1; if (dgm < 0) dgm = 0;
#pragma unroll
        for (int k = 0; k < 8; k++) { int o = k > dgm ? dgm : k; idx[k] = ci[s + o]; }
    }

#pragma unroll
    for (int rr = 0; rr < 2; rr++) {
        int d = r0 + rbase + rr;
        uint4 xdv = make_uint4(0, 0, 0, 0);
        if (d < n_dst) xdv = xd4[(size_t)d * 16 + li16];  // own row, hidden under gathers
        int dg = degv[rr];
        int dgm = dg - 1; if (dgm < 0) dgm = 0;
        float mn[8];
#pragma unroll
        for (int k = 0; k < 8; k++) mn[k] = 1e30f;
        int c = 0;
        for (;;) {
            // 8 independent row gathers (this group's chunk of 8 pairs)
            uint4 u0 = xs4[(size_t)idx[0] * 16 + li16];
            uint4 u1 = xs4[(size_t)idx[1] * 16 + li16];
            uint4 u2 = xs4[(size_t)idx[2] * 16 + li16];
            uint4 u3 = xs4[(size_t)idx[3] * 16 + li16];
            uint4 u4 = xs4[(size_t)idx[4] * 16 + li16];
            uint4 u5 = xs4[(size_t)idx[5] * 16 + li16];
            uint4 u6 = xs4[(size_t)idx[6] * 16 + li16];
            uint4 u7 = xs4[(size_t)idx[7] * 16 + li16];
            int cN = c + 8;
            bool more = cN < dg;
            int idxN[8];
            if (more) {  // next chunk of same row
#pragma unroll
                for (int k = 0; k < 8; k++) {
                    int o = cN + k; o = o > dgm ? dgm : o;
                    idxN[k] = ci[startv[rr] + o];
                }
            } else if (rr == 0) {  // first chunk of next row
                int s2 = startv[1], dgm2 = degv[1] - 1; if (dgm2 < 0) dgm2 = 0;
#pragma unroll
                for (int k = 0; k < 8; k++) { int o = k > dgm2 ? dgm2 : k; idxN[k] = ci[s2 + o]; }
            } else {
#pragma unroll
                for (int k = 0; k < 8; k++) idxN[k] = 0;
            }
            upmin8(mn, u0); upmin8(mn, u1); upmin8(mn, u2); upmin8(mn, u3);
            upmin8(mn, u4); upmin8(mn, u5); upmin8(mn, u6); upmin8(mn, u7);
#pragma unroll
            for (int k = 0; k < 8; k++) idx[k] = idxN[k];
            if (!more) break;
            c = cN;
        }
        // mx = deg ? xd - mn : 0 ; pack to bf16 (lane-local, no shuffle)
        float m0 = dg ? lo16(xdv.x) - mn[0] : 0.f;
        float m1 = dg ? hi16(xdv.x) - mn[1] : 0.f;
        float m2 = dg ? lo16(xdv.y) - mn[2] : 0.f;
        float m3 = dg ? hi16(xdv.y) - mn[3] : 0.f;
        float m4 = dg ? lo16(xdv.z) - mn[4] : 0.f;
        float m5 = dg ? hi16(xdv.z) - mn[5] : 0.f;
        float m6 = dg ? lo16(xdv.w) - mn[6] : 0.f;
        float m7 = dg ? hi16(xdv.w) - mn[7] : 0.f;
        uint4 mxp = make_uint4(pack2bf(m0, m1), pack2bf(m2, m3), pack2bf(m4, m5), pack2bf(m6, m7));
        int r = rbase + rr;
        *(uint4*)&h[r * 264 + li16 * 8] = xdv;
        *(uint4*)&h[r * 264 + 128 + li16 * 8] = mxp;
    }
    __syncthreads();

    // --- MFMA MLP + residual epilogue
    int rt = wave >> 1;
    int ctbase = (wave & 1) * 4;
    int m = lane & 15, q = lane >> 4;
    f32x4 acc[4];
#pragma unroll
    for (int ct = 0; ct < 4; ct++) acc[ct] = (f32x4){0.f, 0.f, 0.f, 0.f};
    for (int k0 = 0; k0 < 256; k0 += 32) {
        bf16x8 a = *(const bf16x8*)&h[(rt * 16 + m) * 264 + k0 + q * 8];
#pragma unroll
        for (int ct = 0; ct < 4; ct++) {
            int n = (ctbase + ct) * 16 + m;
            bf16x8 b = *(const bf16x8*)&Wt[n * 256 + k0 + q * 8];
            acc[ct] = __builtin_amdgcn_mfma_f32_16x16x32_bf16(a, b, acc[ct], 0, 0, 0);
        }
    }
#pragma unroll
    for (int ct = 0; ct < 4; ct++) {
        int col = (ctbase + ct) * 16 + m;
        float bc = bias[col];
#pragma unroll
        for (int reg = 0; reg < 4; reg++) {
            int r_l = rt * 16 + q * 4 + reg;
            int row = r0 + r_l;
            if (row < n_dst) {
                float xold = bfu(h[r_l * 264 + col]);
                float val = xold + lrelu(acc[ct][reg] + bc);
                if (OUT_F32) out_f[(size_t)row * W + col] = val;
                else out_b[(size_t)row * W + col] = f2bf(val);
            }
        }
    }
}

static inline char* alignp(char* p, size_t a) {
    return (char*)(((uintptr_t)p + a - 1) & ~(uintptr_t)(a - 1));
}

extern "C" void kernel_launch(void* const* d_in, const int* in_sizes, int n_in,
                              void* d_out, int out_size, void* d_ws, size_t ws_size,
                              hipStream_t stream) {
    const float* vertices = (const float*)d_in[0];
    const float* edges    = (const float*)d_in[1];
    const float* faces    = (const float*)d_in[2];
    const int* etv_v   = (const int*)d_in[3];
    const int* etv_e   = (const int*)d_in[4];
    const int* fte_e   = (const int*)d_in[5];
    const int* fte_f   = (const int*)d_in[6];
    const int* ftf_src = (const int*)d_in[7];
    const int* ftf_dst = (const int*)d_in[8];
    const float* Wv   = (const float*)d_in[9];
    const float* bv   = (const float*)d_in[10];
    const float* We   = (const float*)d_in[11];
    const float* be   = (const float*)d_in[12];
    const float* Wf   = (const float*)d_in[13];
    const float* bf_  = (const float*)d_in[14];
    const float* Wv2e = (const float*)d_in[15];
    const float* bv2e = (const float*)d_in[16];
    const float* We2f = (const float*)d_in[17];
    const float* be2f = (const float*)d_in[18];
    const float* Wm0  = (const float*)d_in[19];
    const float* bm0  = (const float*)d_in[20];
    const float* Wm1  = (const float*)d_in[21];
    const float* bm1  = (const float*)d_in[22];

    const int NV = in_sizes[0] / 3;
    const int NE = in_sizes[1] / 12;
    const int NF = in_sizes[2] / 14;
    const int N_EV = in_sizes[3];
    const int N_FE = in_sizes[5];
    const int N_FF = in_sizes[7];
    (void)n_in; (void)out_size; (void)ws_size;

    const int D = NE + NF + NF;
    const int NP = N_EV + N_FE + N_FF;
    const int NB = (D + BSZ - 1) >> BSHIFT;

    // ---- ws layout ----
    char* p = (char*)d_ws;
    unsigned short* x_eb = (unsigned short*)p;  p += (size_t)NE * W * sizeof(unsigned short);
    unsigned short* f0b  = (unsigned short*)p;  p += (size_t)NF * W * sizeof(unsigned short);
    unsigned short* f1b  = (unsigned short*)p;  p += (size_t)(NF > NV ? NF : NV) * W * sizeof(unsigned short);
    p = alignp(p, 16);
    int2* pairs = (int2*)p;                     p += (size_t)NP * sizeof(int2);
    int* ci     = (int*)p;                      p += (size_t)(NP + 8) * sizeof(int);
    int* rowptr = (int*)p;                      p += (size_t)(D + 1) * sizeof(int);
    int* gcnt   = (int*)p;                      p += 512 * sizeof(int);
    int* goff   = (int*)p;                      p += 513 * sizeof(int);
    int* gcur   = (int*)p;                      p += 512 * sizeof(int);
    p = alignp(p, 16);
    unsigned short* Wt0 = (unsigned short*)p;   p += (size_t)32768 * sizeof(unsigned short);
    unsigned short* Wt1 = (unsigned short*)p;   p += (size_t)32768 * sizeof(unsigned short);
    unsigned short* Wt2 = (unsigned short*)p;   p += (size_t)32768 * sizeof(unsigned short);
    unsigned short* Wt3 = (unsigned short*)p;   p += (size_t)32768 * sizeof(unsigned short);

    // x_v bf16 embed aliases f1b: x_vb is dead after the V2E conv, and f1b is
    // first written by conv m0 (two convs later on the same stream).
    unsigned short* x_vb = f1b;

    float* out_f = (float*)d_out;
    const int TB = 256;

    // ---- embeds (bf16) ----
    embed_kernel<3><<<((size_t)NV * W + TB - 1) / TB, TB, 0, stream>>>(vertices, Wv, bv, x_vb, NV);
    embed_kernel<12><<<((size_t)NE * W + TB - 1) / TB, TB, 0, stream>>>(edges, We, be, x_eb, NE);
    embed_kernel<14><<<((size_t)NF * W + TB - 1) / TB, TB, 0, stream>>>(faces, Wf, bf_, f0b, NF);
    wconv4_kernel<<<512, TB, 0, stream>>>(Wv2e, We2f, Wm0, Wm1, Wt0, Wt1, Wt2, Wt3);

    // ---- bucket-partitioned CSR build ----
    PairSrc P = {etv_e, etv_v, N_EV, fte_f, fte_e, N_FE, ftf_dst, ftf_src, N_FF, NE, NF};
    (void)hipMemsetAsync(gcnt, 0, 512 * sizeof(int), stream);
    int ablocks = (NP + CHUNK - 1) / CHUNK;
    part_hist<<<ablocks, TB, 0, stream>>>(P, gcnt);
    bucket_scan<<<1, 512, 0, stream>>>(gcnt, goff, gcur, NB, NP);
    part_scatter<<<ablocks, TB, 0, stream>>>(P, gcur, pairs);
    bucket_sort<<<NB, TB, 0, stream>>>(pairs, goff, D, NP, rowptr, ci);

    // ---- fused convs (row-parallel, 16-lane groups, 8-deep gathers) ----
    fused_conv_rp<false><<<(NE + ROWS - 1) / ROWS, TB, 0, stream>>>(
        x_vb, x_eb, x_eb, nullptr, rowptr, ci, Wt0, bv2e, NE);
    fused_conv_rp<false><<<(NF + ROWS - 1) / ROWS, TB, 0, stream>>>(
        x_eb, f0b, f0b, nullptr, rowptr + NE, ci, Wt1, be2f, NF);
    fused_conv_rp<false><<<(NF + ROWS - 1) / ROWS, TB, 0, stream>>>(
        f0b, f0b, f1b, nullptr, rowptr + NE + NF, ci, Wt2, bm0, NF);
    fused_conv_rp<true><<<(NF + ROWS - 1) / ROWS, TB, 0, stream>>>(
        f1b, f1b, nullptr, out_f, rowptr + NE + NF, ci, Wt3, bm1, NF);
}